// Round 1
// baseline (6077.116 us; speedup 1.0000x reference)
//
#include <hip/hip_runtime.h>

// GPT forward: L=4, H=4, C=1024, HS=256, V=32000, B=4, T=1024. f32 in/out,
// bf16 MFMA (16x16x32) compute with f32 accumulate.

#define C_  1024
#define T_  1024
#define HS_ 256
#define H_  4
#define L_  4
#define V_  32000
#define B_  4
#define M_  4096   // B_*T_

typedef __attribute__((ext_vector_type(8))) short  bfx8;
typedef __attribute__((ext_vector_type(4))) float  fx4;
typedef __attribute__((ext_vector_type(4))) unsigned short usx4;

__device__ __forceinline__ unsigned short f2bf(float f) {
  unsigned int u = __builtin_bit_cast(unsigned int, f);
  u += 0x7fffu + ((u >> 16) & 1u);          // round-to-nearest-even
  return (unsigned short)(u >> 16);
}

#define LDK 40   // padded LDS row stride (ushorts): 80B rows, 16B-aligned, bank-spread

// C = act(A@B + bias) (+res). AMODE 0: A is MxK row-major. AMODE 1: A stored KxM.
// BMODE 0: B stored NxK (i.e. B^T, direct stage). BMODE 1: B stored KxN (transpose stage).
// out addr(m,n) = outBase + (z>>zShift)*sC1 + (z&mask)*sC2 + (m>>10)*rowOuter + (m&1023)*ldc + n
template<int AMODE, int BMODE, int BIAS, int RES, int RELU>
__global__ __launch_bounds__(256, 2) void gemm_bf16(
    const float* __restrict__ A, const float* __restrict__ Bm,
    const float* __restrict__ bias, const float* __restrict__ res,
    float* __restrict__ out,
    int M, int N, int K, int lda, int ldb, int ldc,
    long sA, long sB, long sC1, long sC2, int zShift, long rowOuter)
{
  __shared__ unsigned short As[128 * LDK];
  __shared__ unsigned short Bs[128 * LDK];
  const int z = blockIdx.z;
  A  += (long)z * sA;
  Bm += (long)z * sB;
  const long outOff = ((long)(z >> zShift)) * sC1 + (long)(z & ((1 << zShift) - 1)) * sC2;
  const int m0 = blockIdx.y * 128, n0 = blockIdx.x * 128;
  const int tid = threadIdx.x;
  const int lane = tid & 63, wave = tid >> 6;
  const int wm = (wave >> 1) * 64, wn = (wave & 1) * 64;
  const int fr = lane & 15, kb = lane >> 4;

  fx4 acc[4][4] = {};

  for (int k0 = 0; k0 < K; k0 += 32) {
    // ---- stage A tile (128 x 32) as bf16 into As[m][k] ----
    #pragma unroll
    for (int it = 0; it < 4; ++it) {
      const int f = tid + it * 256;
      if (AMODE == 0) {
        const int r = f >> 3, cv = (f & 7) * 4;
        const float4 v = *reinterpret_cast<const float4*>(A + (long)(m0 + r) * lda + k0 + cv);
        usx4 u = { f2bf(v.x), f2bf(v.y), f2bf(v.z), f2bf(v.w) };
        *reinterpret_cast<usx4*>(&As[r * LDK + cv]) = u;
      } else {
        const int kr = f >> 5, mv = (f & 31) * 4;
        const float4 v = *reinterpret_cast<const float4*>(A + (long)(k0 + kr) * lda + m0 + mv);
        As[(mv + 0) * LDK + kr] = f2bf(v.x);
        As[(mv + 1) * LDK + kr] = f2bf(v.y);
        As[(mv + 2) * LDK + kr] = f2bf(v.z);
        As[(mv + 3) * LDK + kr] = f2bf(v.w);
      }
      // ---- stage B tile into Bs[n][k] ----
      if (BMODE == 0) {
        const int r = f >> 3, cv = (f & 7) * 4;
        const float4 v = *reinterpret_cast<const float4*>(Bm + (long)(n0 + r) * ldb + k0 + cv);
        usx4 u = { f2bf(v.x), f2bf(v.y), f2bf(v.z), f2bf(v.w) };
        *reinterpret_cast<usx4*>(&Bs[r * LDK + cv]) = u;
      } else {
        const int kr = f >> 5, nv = (f & 31) * 4;
        const float4 v = *reinterpret_cast<const float4*>(Bm + (long)(k0 + kr) * ldb + n0 + nv);
        Bs[(nv + 0) * LDK + kr] = f2bf(v.x);
        Bs[(nv + 1) * LDK + kr] = f2bf(v.y);
        Bs[(nv + 2) * LDK + kr] = f2bf(v.z);
        Bs[(nv + 3) * LDK + kr] = f2bf(v.w);
      }
    }
    __syncthreads();
    bfx8 af[4], bf[4];
    #pragma unroll
    for (int i = 0; i < 4; ++i)
      af[i] = *reinterpret_cast<const bfx8*>(&As[(wm + i * 16 + fr) * LDK + kb * 8]);
    #pragma unroll
    for (int j = 0; j < 4; ++j)
      bf[j] = *reinterpret_cast<const bfx8*>(&Bs[(wn + j * 16 + fr) * LDK + kb * 8]);
    #pragma unroll
    for (int i = 0; i < 4; ++i)
      #pragma unroll
      for (int j = 0; j < 4; ++j)
        acc[i][j] = __builtin_amdgcn_mfma_f32_16x16x32_bf16(af[i], bf[j], acc[i][j], 0, 0, 0);
    __syncthreads();
  }

  out += outOff;
  const float* resp = res;
  if (RES) resp += outOff;
  const int rbase = (lane >> 4) * 4;
  #pragma unroll
  for (int j = 0; j < 4; ++j) {
    const int n = n0 + wn + j * 16 + fr;
    float bv = 0.f;
    if (BIAS) bv = bias[n];
    #pragma unroll
    for (int i = 0; i < 4; ++i) {
      #pragma unroll
      for (int r = 0; r < 4; ++r) {
        const int m = m0 + wm + i * 16 + rbase + r;
        const long off = ((long)(m >> 10)) * rowOuter + (long)(m & 1023) * ldc + n;
        float val = acc[i][j][r] + bv;
        if (RELU) val = fmaxf(val, 0.f);
        if (RES) val += resp[off];
        out[off] = val;
      }
    }
  }
}

__global__ __launch_bounds__(256) void embed_k(const int* __restrict__ idx,
                                               const float* __restrict__ tok,
                                               const float* __restrict__ pos,
                                               float* __restrict__ x) {
  const int row = blockIdx.x;
  const int t = row & (T_ - 1);
  const int id = idx[row];
  const int c = threadIdx.x * 4;
  const float4 a = *reinterpret_cast<const float4*>(tok + (long)id * C_ + c);
  const float4 p = *reinterpret_cast<const float4*>(pos + (long)t * C_ + c);
  float4 ov = { a.x + p.x, a.y + p.y, a.z + p.z, a.w + p.w };
  *reinterpret_cast<float4*>(x + (long)row * C_ + c) = ov;
}

__global__ __launch_bounds__(256) void ln_k(const float* __restrict__ x,
                                            const float* __restrict__ g,
                                            const float* __restrict__ b,
                                            float* __restrict__ o) {
  __shared__ float red[8];
  const int row = blockIdx.x;
  const int c = threadIdx.x * 4;
  const float4 v = *reinterpret_cast<const float4*>(x + (long)row * C_ + c);
  float s1 = v.x + v.y + v.z + v.w;
  float s2 = v.x * v.x + v.y * v.y + v.z * v.z + v.w * v.w;
  #pragma unroll
  for (int off = 32; off; off >>= 1) {
    s1 += __shfl_xor(s1, off, 64);
    s2 += __shfl_xor(s2, off, 64);
  }
  const int lane = threadIdx.x & 63, w = threadIdx.x >> 6;
  if (lane == 0) { red[w] = s1; red[4 + w] = s2; }
  __syncthreads();
  s1 = red[0] + red[1] + red[2] + red[3];
  s2 = red[4] + red[5] + red[6] + red[7];
  const float mu = s1 * (1.f / C_);
  float var = s2 * (1.f / C_) - mu * mu;
  var = fmaxf(var, 0.f);
  const float inv = rsqrtf(var + 1e-5f);
  const float4 gg = *reinterpret_cast<const float4*>(g + c);
  const float4 bb = *reinterpret_cast<const float4*>(b + c);
  float4 ov;
  ov.x = (v.x - mu) * inv * gg.x + bb.x;
  ov.y = (v.y - mu) * inv * gg.y + bb.y;
  ov.z = (v.z - mu) * inv * gg.z + bb.z;
  ov.w = (v.w - mu) * inv * gg.w + bb.w;
  *reinterpret_cast<float4*>(o + (long)row * C_ + c) = ov;
}

// alphaT rows: row = (b*H+h)*T + s, length T over t. softmax over valid t>=s,
// scale 1/32 applied pre-exp (reference: where(causal,s,-inf)*inv_sqrt_c, softmax axis=t).
__global__ __launch_bounds__(256) void colsm_k(float* __restrict__ a) {
  __shared__ float red[8];
  const int row = blockIdx.x;
  const int s = row & (T_ - 1);
  float* p = a + (long)row * T_;
  const int t0 = threadIdx.x * 4;
  const float4 v = *reinterpret_cast<const float4*>(p + t0);
  const float vv[4] = { v.x, v.y, v.z, v.w };
  const float scale = 0.03125f;  // 1/sqrt(C)=1/32
  float vals[4];
  float m = -1e30f;
  #pragma unroll
  for (int j = 0; j < 4; ++j) {
    vals[j] = (t0 + j >= s) ? vv[j] * scale : -1e30f;
    m = fmaxf(m, vals[j]);
  }
  #pragma unroll
  for (int off = 32; off; off >>= 1) m = fmaxf(m, __shfl_xor(m, off, 64));
  const int lane = threadIdx.x & 63, w = threadIdx.x >> 6;
  if (lane == 0) red[w] = m;
  __syncthreads();
  m = fmaxf(fmaxf(red[0], red[1]), fmaxf(red[2], red[3]));
  __syncthreads();
  float e[4], sum = 0.f;
  #pragma unroll
  for (int j = 0; j < 4; ++j) {
    e[j] = (t0 + j >= s) ? __expf(vals[j] - m) : 0.f;
    sum += e[j];
  }
  #pragma unroll
  for (int off = 32; off; off >>= 1) sum += __shfl_xor(sum, off, 64);
  if (lane == 0) red[w] = sum;
  __syncthreads();
  sum = red[0] + red[1] + red[2] + red[3];
  const float inv = 1.f / sum;
  float4 ov = { e[0] * inv, e[1] * inv, e[2] * inv, e[3] * inv };
  *reinterpret_cast<float4*>(p + t0) = ov;
}

extern "C" void kernel_launch(void* const* d_in, const int* in_sizes, int n_in,
                              void* d_out, int out_size, void* d_ws, size_t ws_size,
                              hipStream_t stream) {
  const int*   idx    = (const int*)d_in[0];
  const float* tok    = (const float*)d_in[1];
  const float* pos    = (const float*)d_in[2];
  const float* wq     = (const float*)d_in[3];
  const float* wk     = (const float*)d_in[4];
  const float* wv     = (const float*)d_in[5];
  const float* proj_w = (const float*)d_in[6];
  const float* proj_b = (const float*)d_in[7];
  const float* ln1_g  = (const float*)d_in[8];
  const float* ln1_b  = (const float*)d_in[9];
  const float* ln2_g  = (const float*)d_in[10];
  const float* ln2_b  = (const float*)d_in[11];
  const float* ff_w1  = (const float*)d_in[12];
  const float* ff_b1  = (const float*)d_in[13];
  const float* ff_w2  = (const float*)d_in[14];
  const float* ff_b2  = (const float*)d_in[15];
  const float* lnf_g  = (const float*)d_in[16];
  const float* lnf_b  = (const float*)d_in[17];
  const float* head_w = (const float*)d_in[18];
  const float* head_b = (const float*)d_in[19];
  float* outp = (float*)d_out;

  const long NX = (long)M_ * C_;   // 4M floats per activation buffer
  float* x   = (float*)d_ws;
  float* xn  = x  + NX;
  float* q   = xn + NX;            // (B,H,T,HS)
  float* k   = q  + NX;
  float* v   = k  + NX;
  float* yc  = v  + NX;            // (B,T,C) attention out, heads concatenated
  float* big = yc + NX;            // alphaT (B*H,T,T) / FF hidden (M,4C) — time-shared
  const size_t need = (size_t)(6 * NX + (long)B_ * H_ * T_ * T_) * 4;
  if (ws_size < need) return;      // fail loudly (output stays poisoned)

  embed_k<<<M_, 256, 0, stream>>>(idx, tok, pos, x);

  for (int l = 0; l < L_; ++l) {
    ln_k<<<M_, 256, 0, stream>>>(x, ln1_g + l * C_, ln1_b + l * C_, xn);

    // q/k/v: per-head GEMM batched over h. out layout (B,H,T,HS).
    dim3 gq(HS_ / 128, M_ / 128, H_);
    const long wls = (long)H_ * C_ * HS_;
    gemm_bf16<0,1,0,0,0><<<gq, 256, 0, stream>>>(xn, wq + (long)l * wls, nullptr, nullptr, q,
        M_, HS_, C_, C_, HS_, HS_, 0, (long)C_ * HS_, (long)T_ * HS_, 0, 0, (long)H_ * T_ * HS_);
    gemm_bf16<0,1,0,0,0><<<gq, 256, 0, stream>>>(xn, wk + (long)l * wls, nullptr, nullptr, k,
        M_, HS_, C_, C_, HS_, HS_, 0, (long)C_ * HS_, (long)T_ * HS_, 0, 0, (long)H_ * T_ * HS_);
    gemm_bf16<0,1,0,0,0><<<gq, 256, 0, stream>>>(xn, wv + (long)l * wls, nullptr, nullptr, v,
        M_, HS_, C_, C_, HS_, HS_, 0, (long)C_ * HS_, (long)T_ * HS_, 0, 0, (long)H_ * T_ * HS_);

    // S^T[s][t] = sum_d K[s,d]*Q[t,d]  -> big[(b*H+h)*T*T], row-major (s,t)
    dim3 gs(T_ / 128, T_ / 128, B_ * H_);
    gemm_bf16<0,0,0,0,0><<<gs, 256, 0, stream>>>(k, q, nullptr, nullptr, big,
        T_, T_, HS_, HS_, HS_, T_, (long)T_ * HS_, (long)T_ * HS_, (long)T_ * T_, 0, 0, (long)T_ * T_);

    // softmax over t (query axis) per (b,h,s) row; mask t<s; scale 1/32.
    colsm_k<<<B_ * H_ * T_, 256, 0, stream>>>(big);

    // y[t,d] = sum_s alphaT[s,t]*v[s,d]; write into yc(B,T,C) at col block h*HS.
    dim3 gp(HS_ / 128, T_ / 128, B_ * H_);
    gemm_bf16<1,1,0,0,0><<<gp, 256, 0, stream>>>(big, v, nullptr, nullptr, yc,
        T_, HS_, T_, T_, HS_, C_, (long)T_ * T_, (long)T_ * HS_, (long)T_ * C_, HS_, 2, (long)T_ * C_);

    // x = x + yc @ proj_w + proj_b
    dim3 gj(C_ / 128, M_ / 128, 1);
    gemm_bf16<0,1,1,1,0><<<gj, 256, 0, stream>>>(yc, proj_w + (long)l * C_ * C_, proj_b + l * C_, x, x,
        M_, C_, C_, C_, C_, C_, 0, 0, 0, 0, 0, (long)T_ * C_);

    ln_k<<<M_, 256, 0, stream>>>(x, ln2_g + l * C_, ln2_b + l * C_, xn);

    // h = relu(xn @ ff_w1 + b1)
    dim3 g1(4 * C_ / 128, M_ / 128, 1);
    gemm_bf16<0,1,1,0,1><<<g1, 256, 0, stream>>>(xn, ff_w1 + (long)l * C_ * 4 * C_, ff_b1 + (long)l * 4 * C_,
        nullptr, big, M_, 4 * C_, C_, C_, 4 * C_, 4 * C_, 0, 0, 0, 0, 0, (long)T_ * 4 * C_);

    // x = x + h @ ff_w2 + b2
    dim3 g2(C_ / 128, M_ / 128, 1);
    gemm_bf16<0,1,1,1,0><<<g2, 256, 0, stream>>>(big, ff_w2 + (long)l * 4 * C_ * C_, ff_b2 + l * C_, x, x,
        M_, C_, 4 * C_, 4 * C_, C_, C_, 0, 0, 0, 0, 0, (long)T_ * C_);
  }

  ln_k<<<M_, 256, 0, stream>>>(x, lnf_g, lnf_b, xn);

  dim3 gh(V_ / 128, M_ / 128, 1);
  gemm_bf16<0,1,1,0,0><<<gh, 256, 0, stream>>>(xn, head_w, head_b, nullptr, outp,
      M_, V_, C_, C_, V_, V_, 0, 0, 0, 0, 0, (long)T_ * V_);
}

// Round 2
// 2078.651 us; speedup vs baseline: 2.9236x; 2.9236x over previous
//
#include <hip/hip_runtime.h>

// GPT forward: L=4, H=4, C=1024, HS=256, V=32000, B=4, T=1024. f32 in/out.
// All GEMMs: bf16 MFMA 16x16x32, f32 accumulate, direct (non-transposed) LDS
// staging only. Weights pre-transposed+converted to bf16 NxK once per launch.

#define C_  1024
#define T_  1024
#define HS_ 256
#define H_  4
#define L_  4
#define V_  32000
#define B_  4
#define M_  4096   // B_*T_

typedef __attribute__((ext_vector_type(8))) short  bfx8;
typedef __attribute__((ext_vector_type(4))) float  fx4;
typedef __attribute__((ext_vector_type(4))) unsigned short usx4;
typedef __attribute__((ext_vector_type(8))) unsigned short usx8;

__device__ __forceinline__ unsigned short f2bf(float f) {
  unsigned int u = __builtin_bit_cast(unsigned int, f);
  u += 0x7fffu + ((u >> 16) & 1u);          // round-to-nearest-even
  return (unsigned short)(u >> 16);
}
__device__ __forceinline__ float bf2f(unsigned short u) {
  return __builtin_bit_cast(float, ((unsigned int)u) << 16);
}

#define LDK 40   // LDS row stride (ushorts): 80 B rows -> 16B-aligned usx8, ~2-way banks

// out[m][n] = act(sum_k A[m][k]*B[n][k] + bias[n]) (+res). A: MxK bf16 row-major.
// B: NxK bf16 row-major. out addr(m,n) = (z>>zShift)*sC1 + (z&mask)*sC2
//                                      + (m>>10)*rowOuter + (m&1023)*ldc + n
template<int BIAS, int RES, int RELU, int OUTBF>
__global__ __launch_bounds__(256, 2) void gemm_bf16(
    const unsigned short* __restrict__ A, const unsigned short* __restrict__ Bm,
    const float* __restrict__ bias, const float* __restrict__ res,
    void* __restrict__ out,
    int M, int N, int K, int lda, int ldb, int ldc,
    long sA, long sB, long sC1, long sC2, int zShift, long rowOuter)
{
  __shared__ unsigned short As[128 * LDK];
  __shared__ unsigned short Bs[128 * LDK];
  const int z = blockIdx.z;
  A  += (long)z * sA;
  Bm += (long)z * sB;
  const long outOff = ((long)(z >> zShift)) * sC1 + (long)(z & ((1 << zShift) - 1)) * sC2;
  const int m0 = blockIdx.y * 128, n0 = blockIdx.x * 128;
  const int tid = threadIdx.x;
  const int lane = tid & 63, wave = tid >> 6;
  const int wm = (wave >> 1) * 64, wn = (wave & 1) * 64;
  const int fr = lane & 15, kb = lane >> 4;

  fx4 acc[4][4] = {};

  for (int k0 = 0; k0 < K; k0 += 32) {
    // stage A,B tiles (128 x 32 bf16 each): 512 x 16B units, 256 thr x 2 iters
    #pragma unroll
    for (int it = 0; it < 2; ++it) {
      const int f = tid + it * 256;
      const int r = f >> 2, u = (f & 3) * 8;
      *reinterpret_cast<usx8*>(&As[r * LDK + u]) =
          *reinterpret_cast<const usx8*>(A + (long)(m0 + r) * lda + k0 + u);
      *reinterpret_cast<usx8*>(&Bs[r * LDK + u]) =
          *reinterpret_cast<const usx8*>(Bm + (long)(n0 + r) * ldb + k0 + u);
    }
    __syncthreads();
    bfx8 af[4], bf[4];
    #pragma unroll
    for (int i = 0; i < 4; ++i)
      af[i] = *reinterpret_cast<const bfx8*>(&As[(wm + i * 16 + fr) * LDK + kb * 8]);
    #pragma unroll
    for (int j = 0; j < 4; ++j)
      bf[j] = *reinterpret_cast<const bfx8*>(&Bs[(wn + j * 16 + fr) * LDK + kb * 8]);
    #pragma unroll
    for (int i = 0; i < 4; ++i)
      #pragma unroll
      for (int j = 0; j < 4; ++j)
        acc[i][j] = __builtin_amdgcn_mfma_f32_16x16x32_bf16(af[i], bf[j], acc[i][j], 0, 0, 0);
    __syncthreads();
  }

  const float* resp = res;
  if (RES) resp += outOff;
  const int rbase = (lane >> 4) * 4;
  #pragma unroll
  for (int j = 0; j < 4; ++j) {
    const int n = n0 + wn + j * 16 + fr;
    float bv = 0.f;
    if (BIAS) bv = bias[n];
    #pragma unroll
    for (int i = 0; i < 4; ++i) {
      #pragma unroll
      for (int r = 0; r < 4; ++r) {
        const int m = m0 + wm + i * 16 + rbase + r;
        const long off = outOff + ((long)(m >> 10)) * rowOuter + (long)(m & 1023) * ldc + n;
        float val = acc[i][j][r] + bv;
        if (RELU) val = fmaxf(val, 0.f);
        if (RES) val += resp[((long)(m >> 10)) * rowOuter + (long)(m & 1023) * ldc + n];
        if (OUTBF) ((unsigned short*)out)[off] = f2bf(val);
        else       ((float*)out)[off] = val;
      }
    }
  }
}

// Tiled transpose + convert-to-bf16. src: (batch, R, Cc) TIN; dst: (batch, Cc, R) bf16.
// R, Cc multiples of 64.
template<typename TIN>
__global__ __launch_bounds__(256) void transpose_k(const TIN* __restrict__ src,
    unsigned short* __restrict__ dst, int R, int Cc) {
  __shared__ float ts[64][65];
  const long zb = blockIdx.z;
  src += zb * (long)R * Cc;
  dst += zb * (long)R * Cc;
  const int r0 = blockIdx.y * 64, c0 = blockIdx.x * 64;
  const int tr = threadIdx.x >> 4;          // 0..15
  const int tc = (threadIdx.x & 15) * 4;    // 0,4,...,60
  #pragma unroll
  for (int it = 0; it < 4; ++it) {
    const int r = tr + it * 16;
    float4 v;
    if constexpr (sizeof(TIN) == 4) {
      v = *reinterpret_cast<const float4*>(src + (long)(r0 + r) * Cc + c0 + tc);
    } else {
      usx4 u = *reinterpret_cast<const usx4*>(src + (long)(r0 + r) * Cc + c0 + tc);
      v.x = bf2f(u[0]); v.y = bf2f(u[1]); v.z = bf2f(u[2]); v.w = bf2f(u[3]);
    }
    ts[r][tc + 0] = v.x; ts[r][tc + 1] = v.y; ts[r][tc + 2] = v.z; ts[r][tc + 3] = v.w;
  }
  __syncthreads();
  #pragma unroll
  for (int it = 0; it < 4; ++it) {
    const int cj = tr + it * 16;            // output row = tile column
    usx4 o = { f2bf(ts[tc + 0][cj]), f2bf(ts[tc + 1][cj]),
               f2bf(ts[tc + 2][cj]), f2bf(ts[tc + 3][cj]) };
    *reinterpret_cast<usx4*>(dst + (long)(c0 + cj) * R + r0 + tc) = o;
  }
}

__global__ __launch_bounds__(256) void embed_k(const int* __restrict__ idx,
                                               const float* __restrict__ tok,
                                               const float* __restrict__ pos,
                                               float* __restrict__ x) {
  const int row = blockIdx.x;
  const int t = row & (T_ - 1);
  const int id = idx[row];
  const int c = threadIdx.x * 4;
  const float4 a = *reinterpret_cast<const float4*>(tok + (long)id * C_ + c);
  const float4 p = *reinterpret_cast<const float4*>(pos + (long)t * C_ + c);
  float4 ov = { a.x + p.x, a.y + p.y, a.z + p.z, a.w + p.w };
  *reinterpret_cast<float4*>(x + (long)row * C_ + c) = ov;
}

// LayerNorm: f32 in, bf16 out.
__global__ __launch_bounds__(256) void ln_k(const float* __restrict__ x,
                                            const float* __restrict__ g,
                                            const float* __restrict__ b,
                                            unsigned short* __restrict__ o) {
  __shared__ float red[8];
  const int row = blockIdx.x;
  const int c = threadIdx.x * 4;
  const float4 v = *reinterpret_cast<const float4*>(x + (long)row * C_ + c);
  float s1 = v.x + v.y + v.z + v.w;
  float s2 = v.x * v.x + v.y * v.y + v.z * v.z + v.w * v.w;
  #pragma unroll
  for (int off = 32; off; off >>= 1) {
    s1 += __shfl_xor(s1, off, 64);
    s2 += __shfl_xor(s2, off, 64);
  }
  const int lane = threadIdx.x & 63, w = threadIdx.x >> 6;
  if (lane == 0) { red[w] = s1; red[4 + w] = s2; }
  __syncthreads();
  s1 = red[0] + red[1] + red[2] + red[3];
  s2 = red[4] + red[5] + red[6] + red[7];
  const float mu = s1 * (1.f / C_);
  float var = s2 * (1.f / C_) - mu * mu;
  var = fmaxf(var, 0.f);
  const float inv = rsqrtf(var + 1e-5f);
  const float4 gg = *reinterpret_cast<const float4*>(g + c);
  const float4 bb = *reinterpret_cast<const float4*>(b + c);
  usx4 ov;
  ov[0] = f2bf((v.x - mu) * inv * gg.x + bb.x);
  ov[1] = f2bf((v.y - mu) * inv * gg.y + bb.y);
  ov[2] = f2bf((v.z - mu) * inv * gg.z + bb.z);
  ov[3] = f2bf((v.w - mu) * inv * gg.w + bb.w);
  *reinterpret_cast<usx4*>(o + (long)row * C_ + c) = ov;
}

// Row softmax on S^T[s][t] (f32), masked to t>=s, scale 1/32; writes bf16 alphaT.
__global__ __launch_bounds__(256) void colsm_k(const float* __restrict__ a,
                                               unsigned short* __restrict__ aT) {
  __shared__ float red[8];
  const int row = blockIdx.x;
  const int s = row & (T_ - 1);
  const float* p = a + (long)row * T_;
  const int t0 = threadIdx.x * 4;
  const float4 v = *reinterpret_cast<const float4*>(p + t0);
  const float vv[4] = { v.x, v.y, v.z, v.w };
  const float scale = 0.03125f;  // 1/sqrt(C)=1/32
  float vals[4];
  float m = -1e30f;
  #pragma unroll
  for (int j = 0; j < 4; ++j) {
    vals[j] = (t0 + j >= s) ? vv[j] * scale : -1e30f;
    m = fmaxf(m, vals[j]);
  }
  #pragma unroll
  for (int off = 32; off; off >>= 1) m = fmaxf(m, __shfl_xor(m, off, 64));
  const int lane = threadIdx.x & 63, w = threadIdx.x >> 6;
  if (lane == 0) red[w] = m;
  __syncthreads();
  m = fmaxf(fmaxf(red[0], red[1]), fmaxf(red[2], red[3]));
  __syncthreads();
  float e[4], sum = 0.f;
  #pragma unroll
  for (int j = 0; j < 4; ++j) {
    e[j] = (t0 + j >= s) ? __expf(vals[j] - m) : 0.f;
    sum += e[j];
  }
  #pragma unroll
  for (int off = 32; off; off >>= 1) sum += __shfl_xor(sum, off, 64);
  if (lane == 0) red[w] = sum;
  __syncthreads();
  sum = red[0] + red[1] + red[2] + red[3];
  const float inv = 1.f / sum;
  usx4 ov = { f2bf(e[0] * inv), f2bf(e[1] * inv), f2bf(e[2] * inv), f2bf(e[3] * inv) };
  *reinterpret_cast<usx4*>(aT + (long)row * T_ + t0) = ov;
}

extern "C" void kernel_launch(void* const* d_in, const int* in_sizes, int n_in,
                              void* d_out, int out_size, void* d_ws, size_t ws_size,
                              hipStream_t stream) {
  const int*   idx    = (const int*)d_in[0];
  const float* tok    = (const float*)d_in[1];
  const float* pos    = (const float*)d_in[2];
  const float* wq     = (const float*)d_in[3];
  const float* wk     = (const float*)d_in[4];
  const float* wv     = (const float*)d_in[5];
  const float* proj_w = (const float*)d_in[6];
  const float* proj_b = (const float*)d_in[7];
  const float* ln1_g  = (const float*)d_in[8];
  const float* ln1_b  = (const float*)d_in[9];
  const float* ln2_g  = (const float*)d_in[10];
  const float* ln2_b  = (const float*)d_in[11];
  const float* ff_w1  = (const float*)d_in[12];
  const float* ff_b1  = (const float*)d_in[13];
  const float* ff_w2  = (const float*)d_in[14];
  const float* ff_b2  = (const float*)d_in[15];
  const float* lnf_g  = (const float*)d_in[16];
  const float* lnf_b  = (const float*)d_in[17];
  const float* head_w = (const float*)d_in[18];
  const float* head_b = (const float*)d_in[19];
  float* outp = (float*)d_out;

  typedef unsigned short us;
  char* w = (char*)d_ws;
  float* x    = (float*)(w + 0);            // 16,777,216 B  (M,C) f32
  us* xn      = (us*)(w + 16777216);        //  8,388,608 B  (M,C) bf16
  us* q       = (us*)(w + 25165824);        //  8,388,608 B  (B,H,T,HS)
  us* k       = (us*)(w + 33554432);        //  8,388,608 B
  us* v       = (us*)(w + 41943040);        //  8,388,608 B
  us* vT      = (us*)(w + 50331648);        //  8,388,608 B  (B,H,HS,T)
  us* yc      = (us*)(w + 58720256);        //  8,388,608 B  (B,T,C)
  float* big  = (float*)(w + 67108864);     // 67,108,864 B  (B*H,T,T) f32 scores
  us* alpha   = (us*)(w + 67108864);        // alias of big (scores dead after softmax)
  us* headT   = (us*)(w + 67108864);        // alias of big (written after last alpha use)
  us* aT      = (us*)(w + 134217728);       // 33,554,432 B  (B*H,T,T) bf16
  us* hidden  = aT;                         // alias (aT dead after alpha transpose)
  us* wqT     = (us*)(w + 167772160);       //  8,388,608 B  (L,H,HS,C)
  us* wkT     = (us*)(w + 176160768);
  us* wvT     = (us*)(w + 184549376);
  us* projT   = (us*)(w + 192937984);       //  8,388,608 B  (L,C,C)
  us* ff1T    = (us*)(w + 201326592);       // 33,554,432 B  (L,4C,C)
  us* ff2T    = (us*)(w + 234881024);       // 33,554,432 B  (L,C,4C)
  if (ws_size < (size_t)268435456) return;  // fail loudly (output stays poisoned)

  // ---- one-time weight transpose + bf16 convert (graph-safe, deterministic) ----
  transpose_k<float><<<dim3(HS_/64, C_/64, L_*H_), 256, 0, stream>>>(wq, wqT, C_, HS_);
  transpose_k<float><<<dim3(HS_/64, C_/64, L_*H_), 256, 0, stream>>>(wk, wkT, C_, HS_);
  transpose_k<float><<<dim3(HS_/64, C_/64, L_*H_), 256, 0, stream>>>(wv, wvT, C_, HS_);
  transpose_k<float><<<dim3(C_/64, C_/64, L_), 256, 0, stream>>>(proj_w, projT, C_, C_);
  transpose_k<float><<<dim3(4*C_/64, C_/64, L_), 256, 0, stream>>>(ff_w1, ff1T, C_, 4*C_);
  transpose_k<float><<<dim3(C_/64, 4*C_/64, L_), 256, 0, stream>>>(ff_w2, ff2T, 4*C_, C_);

  embed_k<<<M_, 256, 0, stream>>>(idx, tok, pos, x);

  for (int l = 0; l < L_; ++l) {
    ln_k<<<M_, 256, 0, stream>>>(x, ln1_g + l * C_, ln1_b + l * C_, xn);

    // q/k/v (B,H,T,HS) bf16
    dim3 gq(HS_/128, M_/128, H_);
    const long wls = (long)H_ * HS_ * C_;
    gemm_bf16<0,0,0,1><<<gq, 256, 0, stream>>>(xn, wqT + l * wls, nullptr, nullptr, q,
        M_, HS_, C_, C_, C_, HS_, 0, (long)HS_*C_, (long)T_*HS_, 0, 0, (long)H_*T_*HS_);
    gemm_bf16<0,0,0,1><<<gq, 256, 0, stream>>>(xn, wkT + l * wls, nullptr, nullptr, k,
        M_, HS_, C_, C_, C_, HS_, 0, (long)HS_*C_, (long)T_*HS_, 0, 0, (long)H_*T_*HS_);
    gemm_bf16<0,0,0,1><<<gq, 256, 0, stream>>>(xn, wvT + l * wls, nullptr, nullptr, v,
        M_, HS_, C_, C_, C_, HS_, 0, (long)HS_*C_, (long)T_*HS_, 0, 0, (long)H_*T_*HS_);

    // S^T[s][t] = sum_d K[s,d]*Q[t,d]  (f32)
    dim3 gs(T_/128, T_/128, B_*H_);
    gemm_bf16<0,0,0,0><<<gs, 256, 0, stream>>>(k, q, nullptr, nullptr, big,
        T_, T_, HS_, HS_, HS_, T_, (long)T_*HS_, (long)T_*HS_, (long)T_*T_, 0, 0, (long)T_*T_);

    // softmax over t (query axis) per (b,h,s) row -> bf16 alphaT
    colsm_k<<<B_*H_*T_, 256, 0, stream>>>(big, aT);

    // alphaT (s,t) -> alpha (t,s); v (t,d) -> vT (d,t)
    transpose_k<us><<<dim3(T_/64, T_/64, B_*H_), 256, 0, stream>>>(aT, alpha, T_, T_);
    transpose_k<us><<<dim3(HS_/64, T_/64, B_*H_), 256, 0, stream>>>(v, vT, T_, HS_);

    // y[t,d] = sum_s alpha[t,s]*vT[d,s] -> yc (B,T,C) at col h*HS, bf16
    dim3 gp(HS_/128, T_/128, B_*H_);
    gemm_bf16<0,0,0,1><<<gp, 256, 0, stream>>>(alpha, vT, nullptr, nullptr, yc,
        T_, HS_, T_, T_, T_, C_, (long)T_*T_, (long)HS_*T_, (long)T_*C_, HS_, 2, (long)T_*C_);

    // x = x + yc @ proj_w + proj_b   (f32 out)
    dim3 gj(C_/128, M_/128, 1);
    gemm_bf16<1,1,0,0><<<gj, 256, 0, stream>>>(yc, projT + (long)l*C_*C_, proj_b + l*C_, x, x,
        M_, C_, C_, C_, C_, C_, 0, 0, 0, 0, 0, (long)T_*C_);

    ln_k<<<M_, 256, 0, stream>>>(x, ln2_g + l * C_, ln2_b + l * C_, xn);

    // hidden = relu(xn @ ff_w1 + b1)  bf16
    dim3 g1(4*C_/128, M_/128, 1);
    gemm_bf16<1,0,1,1><<<g1, 256, 0, stream>>>(xn, ff1T + (long)l*4*C_*C_, ff_b1 + (long)l*4*C_,
        nullptr, hidden, M_, 4*C_, C_, C_, C_, 4*C_, 0, 0, 0, 0, 0, (long)T_*4*C_);

    // x = x + hidden @ ff_w2 + b2   (f32 out)
    dim3 g2(C_/128, M_/128, 1);
    gemm_bf16<1,1,0,0><<<g2, 256, 0, stream>>>(hidden, ff2T + (long)l*C_*4*C_, ff_b2 + l*C_, x, x,
        M_, C_, 4*C_, 4*C_, 4*C_, C_, 0, 0, 0, 0, 0, (long)T_*C_);
  }

  ln_k<<<M_, 256, 0, stream>>>(x, lnf_g, lnf_b, xn);

  // head weight transpose into the (now dead) scores/alpha region
  transpose_k<float><<<dim3(V_/64, C_/64, 1), 256, 0, stream>>>(head_w, headT, C_, V_);

  dim3 gh(V_/128, M_/128, 1);
  gemm_bf16<1,0,0,0><<<gh, 256, 0, stream>>>(xn, headT, head_b, nullptr, outp,
      M_, V_, C_, C_, C_, V_, 0, 0, 0, 0, 0, (long)T_*V_);
}

// Round 3
// 1902.814 us; speedup vs baseline: 3.1938x; 1.0924x over previous
//
#include <hip/hip_runtime.h>

// GPT forward: L=4, H=4, C=1024, HS=256, V=32000, B=4, T=1024. f32 in/out.
// All GEMMs: bf16 MFMA 16x16x32, f32 accumulate, global_load_lds staging into
// linear LDS (m97 structure). Weights pre-transposed+converted to bf16 NxK.

#define C_  1024
#define T_  1024
#define HS_ 256
#define H_  4
#define L_  4
#define V_  32000
#define B_  4
#define M_  4096   // B_*T_

typedef __attribute__((ext_vector_type(8))) short  bfx8;
typedef __attribute__((ext_vector_type(4))) float  fx4;
typedef __attribute__((ext_vector_type(4))) unsigned short usx4;
typedef __attribute__((ext_vector_type(8))) unsigned short usx8;

__device__ __forceinline__ unsigned short f2bf(float f) {
  unsigned int u = __builtin_bit_cast(unsigned int, f);
  u += 0x7fffu + ((u >> 16) & 1u);          // round-to-nearest-even
  return (unsigned short)(u >> 16);
}
__device__ __forceinline__ float bf2f(unsigned short u) {
  return __builtin_bit_cast(float, ((unsigned int)u) << 16);
}

// async global->LDS, 16 B per lane. LDS dest = (wave-uniform base) + lane*16.
__device__ __forceinline__ void gload16(const unsigned short* g, unsigned short* l) {
  __builtin_amdgcn_global_load_lds(
      (const __attribute__((address_space(1))) unsigned int*)g,
      (__attribute__((address_space(3))) unsigned int*)l, 16, 0, 0);
}

// out[m][n] = act(sum_k A[m][k]*B[n][k] + bias[n]) (+res). A: MxK bf16 row-major.
// B: NxK bf16 row-major. m0 = blockIdx.x*128 (fast axis -> B-panel L2 reuse).
// out addr(m,n) = (z>>zShift)*sC1 + (z&mask)*sC2 + (m>>10)*rowOuter + (m&1023)*ldc + n
template<int BIAS, int RES, int RELU, int OUTBF>
__global__ __launch_bounds__(256, 2) void gemm_bf16(
    const unsigned short* __restrict__ A, const unsigned short* __restrict__ Bm,
    const float* __restrict__ bias, const float* __restrict__ res,
    void* __restrict__ out,
    int M, int N, int K, int lda, int ldb, int ldc,
    long sA, long sB, long sC1, long sC2, int zShift, long rowOuter)
{
  __shared__ unsigned short As[128 * 32];   // linear: row stride 32 us (64 B)
  __shared__ unsigned short Bs[128 * 32];
  const int z = blockIdx.z;
  A  += (long)z * sA;
  Bm += (long)z * sB;
  const long outOff = ((long)(z >> zShift)) * sC1 + (long)(z & ((1 << zShift) - 1)) * sC2;
  const int m0 = blockIdx.x * 128, n0 = blockIdx.y * 128;
  const int tid = threadIdx.x;
  const int lane = tid & 63, wave = tid >> 6;
  const int wm = (wave >> 1) * 64, wn = (wave & 1) * 64;
  const int fr = lane & 15, kb = lane >> 4;
  const int sr = lane >> 2, scb = (lane & 3) * 8;   // staging: row-in-chunk, col (us)

  fx4 acc[4][4] = {};

  for (int k0 = 0; k0 < K; k0 += 32) {
    // stage A,B (128x32 bf16 each) via global_load_lds: 8 chunks of 16 rows,
    // wave w issues chunks 2w,2w+1 for both matrices. 1 KB per wave-instruction.
    #pragma unroll
    for (int i = 0; i < 2; ++i) {
      const int c = wave * 2 + i;
      gload16(A  + (long)(m0 + c * 16 + sr) * lda + k0 + scb, &As[c * 512]);
      gload16(Bm + (long)(n0 + c * 16 + sr) * ldb + k0 + scb, &Bs[c * 512]);
    }
    __syncthreads();   // compiler emits vmcnt(0) drain before barrier
    bfx8 af[4], bf[4];
    #pragma unroll
    for (int i = 0; i < 4; ++i)
      af[i] = *reinterpret_cast<const bfx8*>(&As[(wm + i * 16 + fr) * 32 + kb * 8]);
    #pragma unroll
    for (int j = 0; j < 4; ++j)
      bf[j] = *reinterpret_cast<const bfx8*>(&Bs[(wn + j * 16 + fr) * 32 + kb * 8]);
    #pragma unroll
    for (int i = 0; i < 4; ++i)
      #pragma unroll
      for (int j = 0; j < 4; ++j)
        acc[i][j] = __builtin_amdgcn_mfma_f32_16x16x32_bf16(af[i], bf[j], acc[i][j], 0, 0, 0);
    __syncthreads();
  }

  const float* resp = res;
  if (RES) resp += outOff;
  const int rbase = (lane >> 4) * 4;
  #pragma unroll
  for (int j = 0; j < 4; ++j) {
    const int n = n0 + wn + j * 16 + fr;
    float bv = 0.f;
    if (BIAS) bv = bias[n];
    #pragma unroll
    for (int i = 0; i < 4; ++i) {
      #pragma unroll
      for (int r = 0; r < 4; ++r) {
        const int m = m0 + wm + i * 16 + rbase + r;
        const long off = outOff + ((long)(m >> 10)) * rowOuter + (long)(m & 1023) * ldc + n;
        float val = acc[i][j][r] + bv;
        if (RELU) val = fmaxf(val, 0.f);
        if (RES) val += resp[((long)(m >> 10)) * rowOuter + (long)(m & 1023) * ldc + n];
        if (OUTBF) ((unsigned short*)out)[off] = f2bf(val);
        else       ((float*)out)[off] = val;
      }
    }
  }
}

// Tiled transpose + convert-to-bf16. src: (batch, R, Cc) TIN; dst: (batch, Cc, R) bf16.
template<typename TIN>
__global__ __launch_bounds__(256) void transpose_k(const TIN* __restrict__ src,
    unsigned short* __restrict__ dst, int R, int Cc) {
  __shared__ float ts[64][65];
  const long zb = blockIdx.z;
  src += zb * (long)R * Cc;
  dst += zb * (long)R * Cc;
  const int r0 = blockIdx.y * 64, c0 = blockIdx.x * 64;
  const int tr = threadIdx.x >> 4;          // 0..15
  const int tc = (threadIdx.x & 15) * 4;    // 0,4,...,60
  #pragma unroll
  for (int it = 0; it < 4; ++it) {
    const int r = tr + it * 16;
    float4 v;
    if constexpr (sizeof(TIN) == 4) {
      v = *reinterpret_cast<const float4*>(src + (long)(r0 + r) * Cc + c0 + tc);
    } else {
      usx4 u = *reinterpret_cast<const usx4*>(src + (long)(r0 + r) * Cc + c0 + tc);
      v.x = bf2f(u[0]); v.y = bf2f(u[1]); v.z = bf2f(u[2]); v.w = bf2f(u[3]);
    }
    ts[r][tc + 0] = v.x; ts[r][tc + 1] = v.y; ts[r][tc + 2] = v.z; ts[r][tc + 3] = v.w;
  }
  __syncthreads();
  #pragma unroll
  for (int it = 0; it < 4; ++it) {
    const int cj = tr + it * 16;            // output row = tile column
    usx4 o = { f2bf(ts[tc + 0][cj]), f2bf(ts[tc + 1][cj]),
               f2bf(ts[tc + 2][cj]), f2bf(ts[tc + 3][cj]) };
    *reinterpret_cast<usx4*>(dst + (long)(c0 + cj) * R + r0 + tc) = o;
  }
}

__global__ __launch_bounds__(256) void embed_k(const int* __restrict__ idx,
                                               const float* __restrict__ tok,
                                               const float* __restrict__ pos,
                                               float* __restrict__ x) {
  const int row = blockIdx.x;
  const int t = row & (T_ - 1);
  const int id = idx[row];
  const int c = threadIdx.x * 4;
  const float4 a = *reinterpret_cast<const float4*>(tok + (long)id * C_ + c);
  const float4 p = *reinterpret_cast<const float4*>(pos + (long)t * C_ + c);
  float4 ov = { a.x + p.x, a.y + p.y, a.z + p.z, a.w + p.w };
  *reinterpret_cast<float4*>(x + (long)row * C_ + c) = ov;
}

// LayerNorm: f32 in, bf16 out.
__global__ __launch_bounds__(256) void ln_k(const float* __restrict__ x,
                                            const float* __restrict__ g,
                                            const float* __restrict__ b,
                                            unsigned short* __restrict__ o) {
  __shared__ float red[8];
  const int row = blockIdx.x;
  const int c = threadIdx.x * 4;
  const float4 v = *reinterpret_cast<const float4*>(x + (long)row * C_ + c);
  float s1 = v.x + v.y + v.z + v.w;
  float s2 = v.x * v.x + v.y * v.y + v.z * v.z + v.w * v.w;
  #pragma unroll
  for (int off = 32; off; off >>= 1) {
    s1 += __shfl_xor(s1, off, 64);
    s2 += __shfl_xor(s2, off, 64);
  }
  const int lane = threadIdx.x & 63, w = threadIdx.x >> 6;
  if (lane == 0) { red[w] = s1; red[4 + w] = s2; }
  __syncthreads();
  s1 = red[0] + red[1] + red[2] + red[3];
  s2 = red[4] + red[5] + red[6] + red[7];
  const float mu = s1 * (1.f / C_);
  float var = s2 * (1.f / C_) - mu * mu;
  var = fmaxf(var, 0.f);
  const float inv = rsqrtf(var + 1e-5f);
  const float4 gg = *reinterpret_cast<const float4*>(g + c);
  const float4 bb = *reinterpret_cast<const float4*>(b + c);
  usx4 ov;
  ov[0] = f2bf((v.x - mu) * inv * gg.x + bb.x);
  ov[1] = f2bf((v.y - mu) * inv * gg.y + bb.y);
  ov[2] = f2bf((v.z - mu) * inv * gg.z + bb.z);
  ov[3] = f2bf((v.w - mu) * inv * gg.w + bb.w);
  *reinterpret_cast<usx4*>(o + (long)row * C_ + c) = ov;
}

// Row softmax on S^T[s][t] (f32), masked to t>=s, scale 1/32; writes bf16 alphaT.
__global__ __launch_bounds__(256) void colsm_k(const float* __restrict__ a,
                                               unsigned short* __restrict__ aT) {
  __shared__ float red[8];
  const int row = blockIdx.x;
  const int s = row & (T_ - 1);
  const float* p = a + (long)row * T_;
  const int t0 = threadIdx.x * 4;
  const float4 v = *reinterpret_cast<const float4*>(p + t0);
  const float vv[4] = { v.x, v.y, v.z, v.w };
  const float scale = 0.03125f;  // 1/sqrt(C)=1/32
  float vals[4];
  float m = -1e30f;
  #pragma unroll
  for (int j = 0; j < 4; ++j) {
    vals[j] = (t0 + j >= s) ? vv[j] * scale : -1e30f;
    m = fmaxf(m, vals[j]);
  }
  #pragma unroll
  for (int off = 32; off; off >>= 1) m = fmaxf(m, __shfl_xor(m, off, 64));
  const int lane = threadIdx.x & 63, w = threadIdx.x >> 6;
  if (lane == 0) red[w] = m;
  __syncthreads();
  m = fmaxf(fmaxf(red[0], red[1]), fmaxf(red[2], red[3]));
  __syncthreads();
  float e[4], sum = 0.f;
  #pragma unroll
  for (int j = 0; j < 4; ++j) {
    e[j] = (t0 + j >= s) ? __expf(vals[j] - m) : 0.f;
    sum += e[j];
  }
  #pragma unroll
  for (int off = 32; off; off >>= 1) sum += __shfl_xor(sum, off, 64);
  if (lane == 0) red[w] = sum;
  __syncthreads();
  sum = red[0] + red[1] + red[2] + red[3];
  const float inv = 1.f / sum;
  usx4 ov = { f2bf(e[0] * inv), f2bf(e[1] * inv), f2bf(e[2] * inv), f2bf(e[3] * inv) };
  *reinterpret_cast<usx4*>(aT + (long)row * T_ + t0) = ov;
}

extern "C" void kernel_launch(void* const* d_in, const int* in_sizes, int n_in,
                              void* d_out, int out_size, void* d_ws, size_t ws_size,
                              hipStream_t stream) {
  const int*   idx    = (const int*)d_in[0];
  const float* tok    = (const float*)d_in[1];
  const float* pos    = (const float*)d_in[2];
  const float* wq     = (const float*)d_in[3];
  const float* wk     = (const float*)d_in[4];
  const float* wv     = (const float*)d_in[5];
  const float* proj_w = (const float*)d_in[6];
  const float* proj_b = (const float*)d_in[7];
  const float* ln1_g  = (const float*)d_in[8];
  const float* ln1_b  = (const float*)d_in[9];
  const float* ln2_g  = (const float*)d_in[10];
  const float* ln2_b  = (const float*)d_in[11];
  const float* ff_w1  = (const float*)d_in[12];
  const float* ff_b1  = (const float*)d_in[13];
  const float* ff_w2  = (const float*)d_in[14];
  const float* ff_b2  = (const float*)d_in[15];
  const float* lnf_g  = (const float*)d_in[16];
  const float* lnf_b  = (const float*)d_in[17];
  const float* head_w = (const float*)d_in[18];
  const float* head_b = (const float*)d_in[19];
  float* outp = (float*)d_out;

  typedef unsigned short us;
  char* w = (char*)d_ws;
  float* x    = (float*)(w + 0);            // 16,777,216 B  (M,C) f32
  us* xn      = (us*)(w + 16777216);        //  8,388,608 B  (M,C) bf16
  us* q       = (us*)(w + 25165824);        //  8,388,608 B  (B,H,T,HS)
  us* k       = (us*)(w + 33554432);        //  8,388,608 B
  us* v       = (us*)(w + 41943040);        //  8,388,608 B
  us* vT      = (us*)(w + 50331648);        //  8,388,608 B  (B,H,HS,T)
  us* yc      = (us*)(w + 58720256);        //  8,388,608 B  (B,T,C)
  float* big  = (float*)(w + 67108864);     // 67,108,864 B  (B*H,T,T) f32 scores
  us* alpha   = (us*)(w + 67108864);        // alias of big (scores dead after softmax)
  us* headT   = (us*)(w + 67108864);        // alias of big (written after last alpha use)
  us* aT      = (us*)(w + 134217728);       // 33,554,432 B  (B*H,T,T) bf16
  us* hidden  = aT;                         // alias (aT dead after alpha transpose)
  us* wqT     = (us*)(w + 167772160);       //  8,388,608 B  (L,H,HS,C)
  us* wkT     = (us*)(w + 176160768);
  us* wvT     = (us*)(w + 184549376);
  us* projT   = (us*)(w + 192937984);       //  8,388,608 B  (L,C,C)
  us* ff1T    = (us*)(w + 201326592);       // 33,554,432 B  (L,4C,C)
  us* ff2T    = (us*)(w + 234881024);       // 33,554,432 B  (L,C,4C)
  if (ws_size < (size_t)268435456) return;  // fail loudly (output stays poisoned)

  // ---- one-time weight transpose + bf16 convert ----
  transpose_k<float><<<dim3(HS_/64, C_/64, L_*H_), 256, 0, stream>>>(wq, wqT, C_, HS_);
  transpose_k<float><<<dim3(HS_/64, C_/64, L_*H_), 256, 0, stream>>>(wk, wkT, C_, HS_);
  transpose_k<float><<<dim3(HS_/64, C_/64, L_*H_), 256, 0, stream>>>(wv, wvT, C_, HS_);
  transpose_k<float><<<dim3(C_/64, C_/64, L_), 256, 0, stream>>>(proj_w, projT, C_, C_);
  transpose_k<float><<<dim3(4*C_/64, C_/64, L_), 256, 0, stream>>>(ff_w1, ff1T, C_, 4*C_);
  transpose_k<float><<<dim3(C_/64, 4*C_/64, L_), 256, 0, stream>>>(ff_w2, ff2T, 4*C_, C_);

  embed_k<<<M_, 256, 0, stream>>>(idx, tok, pos, x);

  for (int l = 0; l < L_; ++l) {
    ln_k<<<M_, 256, 0, stream>>>(x, ln1_g + l * C_, ln1_b + l * C_, xn);

    // q/k/v (B,H,T,HS) bf16. grid = (Mblocks, Nblocks, z)
    dim3 gq(M_/128, HS_/128, H_);
    const long wls = (long)H_ * HS_ * C_;
    gemm_bf16<0,0,0,1><<<gq, 256, 0, stream>>>(xn, wqT + l * wls, nullptr, nullptr, q,
        M_, HS_, C_, C_, C_, HS_, 0, (long)HS_*C_, (long)T_*HS_, 0, 0, (long)H_*T_*HS_);
    gemm_bf16<0,0,0,1><<<gq, 256, 0, stream>>>(xn, wkT + l * wls, nullptr, nullptr, k,
        M_, HS_, C_, C_, C_, HS_, 0, (long)HS_*C_, (long)T_*HS_, 0, 0, (long)H_*T_*HS_);
    gemm_bf16<0,0,0,1><<<gq, 256, 0, stream>>>(xn, wvT + l * wls, nullptr, nullptr, v,
        M_, HS_, C_, C_, C_, HS_, 0, (long)HS_*C_, (long)T_*HS_, 0, 0, (long)H_*T_*HS_);

    // S^T[s][t] = sum_d K[s,d]*Q[t,d]  (f32)
    dim3 gs(T_/128, T_/128, B_*H_);
    gemm_bf16<0,0,0,0><<<gs, 256, 0, stream>>>(k, q, nullptr, nullptr, big,
        T_, T_, HS_, HS_, HS_, T_, (long)T_*HS_, (long)T_*HS_, (long)T_*T_, 0, 0, (long)T_*T_);

    // softmax over t (query axis) per (b,h,s) row -> bf16 alphaT
    colsm_k<<<B_*H_*T_, 256, 0, stream>>>(big, aT);

    // alphaT (s,t) -> alpha (t,s); v (t,d) -> vT (d,t)
    transpose_k<us><<<dim3(T_/64, T_/64, B_*H_), 256, 0, stream>>>(aT, alpha, T_, T_);
    transpose_k<us><<<dim3(HS_/64, T_/64, B_*H_), 256, 0, stream>>>(v, vT, T_, HS_);

    // y[t,d] = sum_s alpha[t,s]*vT[d,s] -> yc (B,T,C) at col h*HS, bf16
    dim3 gp(T_/128, HS_/128, B_*H_);
    gemm_bf16<0,0,0,1><<<gp, 256, 0, stream>>>(alpha, vT, nullptr, nullptr, yc,
        T_, HS_, T_, T_, T_, C_, (long)T_*T_, (long)HS_*T_, (long)T_*C_, HS_, 2, (long)T_*C_);

    // x = x + yc @ proj_w + proj_b   (f32 out)
    dim3 gj(M_/128, C_/128, 1);
    gemm_bf16<1,1,0,0><<<gj, 256, 0, stream>>>(yc, projT + (long)l*C_*C_, proj_b + l*C_, x, x,
        M_, C_, C_, C_, C_, C_, 0, 0, 0, 0, 0, (long)T_*C_);

    ln_k<<<M_, 256, 0, stream>>>(x, ln2_g + l * C_, ln2_b + l * C_, xn);

    // hidden = relu(xn @ ff_w1 + b1)  bf16
    dim3 g1(M_/128, 4*C_/128, 1);
    gemm_bf16<1,0,1,1><<<g1, 256, 0, stream>>>(xn, ff1T + (long)l*4*C_*C_, ff_b1 + (long)l*4*C_,
        nullptr, hidden, M_, 4*C_, C_, C_, C_, 4*C_, 0, 0, 0, 0, 0, (long)T_*4*C_);

    // x = x + hidden @ ff_w2 + b2   (f32 out)
    dim3 g2(M_/128, C_/128, 1);
    gemm_bf16<1,1,0,0><<<g2, 256, 0, stream>>>(hidden, ff2T + (long)l*C_*4*C_, ff_b2 + l*C_, x, x,
        M_, C_, 4*C_, 4*C_, 4*C_, C_, 0, 0, 0, 0, 0, (long)T_*C_);
  }

  ln_k<<<M_, 256, 0, stream>>>(x, lnf_g, lnf_b, xn);

  // head weight transpose into the (now dead) scores/alpha region
  transpose_k<float><<<dim3(V_/64, C_/64, 1), 256, 0, stream>>>(head_w, headT, C_, V_);

  dim3 gh(M_/128, V_/128, 1);
  gemm_bf16<1,0,0,0><<<gh, 256, 0, stream>>>(xn, headT, head_b, nullptr, outp,
      M_, V_, C_, C_, C_, V_, 0, 0, 0, 0, 0, (long)T_*V_);
}

// Round 4
// 1853.712 us; speedup vs baseline: 3.2783x; 1.0265x over previous
//
#include <hip/hip_runtime.h>

// GPT forward: L=4, H=4, C=1024, HS=256, V=32000, B=4, T=1024. f32 in/out.
// bf16 MFMA 16x16x32. Big GEMMs (head, FF1, scores): 256x256-tile 8-wave
// deep-pipelined kernel (3-buffer LDS, counted vmcnt, T2 swizzle, setprio).
// Small-N GEMMs: 128x128 m97-structure kernel with T2 swizzle.

#define C_  1024
#define T_  1024
#define HS_ 256
#define H_  4
#define L_  4
#define V_  32000
#define B_  4
#define M_  4096   // B_*T_

typedef __attribute__((ext_vector_type(8))) short  bfx8;
typedef __attribute__((ext_vector_type(4))) float  fx4;
typedef __attribute__((ext_vector_type(4))) unsigned short usx4;

__device__ __forceinline__ unsigned short f2bf(float f) {
  unsigned int u = __builtin_bit_cast(unsigned int, f);
  u += 0x7fffu + ((u >> 16) & 1u);          // round-to-nearest-even
  return (unsigned short)(u >> 16);
}
__device__ __forceinline__ float bf2f(unsigned short u) {
  return __builtin_bit_cast(float, ((unsigned int)u) << 16);
}

// async global->LDS, 16 B per lane. LDS dest = (wave-uniform base) + lane*16.
__device__ __forceinline__ void gload16(const unsigned short* g, unsigned short* l) {
  __builtin_amdgcn_global_load_lds(
      (const __attribute__((address_space(1))) unsigned int*)g,
      (__attribute__((address_space(3))) unsigned int*)l, 16, 0, 0);
}

// ============================ 128x128 kernel =================================
// out[m][n] = act(sum_k A[m][k]*B[n][k] + bias[n]) (+res). A,B bf16 row-major.
// LDS rows are 32 us = 64 B = 4 16B-slots; swizzle: slot ^= (row>>1)&3
// (2 lanes/slot on fragment reads -> free). global source pre-swizzled.
template<int BIAS, int RES, int RELU, int OUTBF>
__global__ __launch_bounds__(256, 2) void gemm_bf16(
    const unsigned short* __restrict__ A, const unsigned short* __restrict__ Bm,
    const float* __restrict__ bias, const float* __restrict__ res,
    void* __restrict__ out,
    int M, int N, int K, int lda, int ldb, int ldc,
    long sA, long sB, long sC1, long sC2, int zShift, long rowOuter)
{
  __shared__ unsigned short As[128 * 32];
  __shared__ unsigned short Bs[128 * 32];
  const int z = blockIdx.z;
  A  += (long)z * sA;
  Bm += (long)z * sB;
  const long outOff = ((long)(z >> zShift)) * sC1 + (long)(z & ((1 << zShift) - 1)) * sC2;
  const int m0 = blockIdx.x * 128, n0 = blockIdx.y * 128;
  const int tid = threadIdx.x;
  const int lane = tid & 63, wave = tid >> 6;
  const int wm = (wave >> 1) * 64, wn = (wave & 1) * 64;
  const int fr = lane & 15, kb = lane >> 4;
  const int sr = lane >> 2;                              // staging row-in-chunk
  const int csw = (((lane & 3) ^ ((lane >> 3) & 3)) << 3); // pre-swizzled src col (us)
  const int aco = ((kb ^ ((lane >> 1) & 3)) << 3);         // swizzled read col (us)

  fx4 acc[4][4] = {};

  for (int k0 = 0; k0 < K; k0 += 32) {
    #pragma unroll
    for (int i = 0; i < 2; ++i) {
      const int c = wave * 2 + i;
      gload16(A  + (long)(m0 + c * 16 + sr) * lda + k0 + csw, &As[c * 512]);
      gload16(Bm + (long)(n0 + c * 16 + sr) * ldb + k0 + csw, &Bs[c * 512]);
    }
    __syncthreads();
    bfx8 af[4], bf[4];
    #pragma unroll
    for (int i = 0; i < 4; ++i)
      af[i] = *reinterpret_cast<const bfx8*>(&As[(wm + i * 16 + fr) * 32 + aco]);
    #pragma unroll
    for (int j = 0; j < 4; ++j)
      bf[j] = *reinterpret_cast<const bfx8*>(&Bs[(wn + j * 16 + fr) * 32 + aco]);
    #pragma unroll
    for (int i = 0; i < 4; ++i)
      #pragma unroll
      for (int j = 0; j < 4; ++j)
        acc[i][j] = __builtin_amdgcn_mfma_f32_16x16x32_bf16(af[i], bf[j], acc[i][j], 0, 0, 0);
    __syncthreads();
  }

  const float* resp = res;
  if (RES) resp += outOff;
  const int rbase = (lane >> 4) * 4;
  #pragma unroll
  for (int j = 0; j < 4; ++j) {
    const int n = n0 + wn + j * 16 + fr;
    float bv = 0.f;
    if (BIAS) bv = bias[n];
    #pragma unroll
    for (int i = 0; i < 4; ++i) {
      #pragma unroll
      for (int r = 0; r < 4; ++r) {
        const int m = m0 + wm + i * 16 + rbase + r;
        const long off = outOff + ((long)(m >> 10)) * rowOuter + (long)(m & 1023) * ldc + n;
        float val = acc[i][j][r] + bv;
        if (RELU) val = fmaxf(val, 0.f);
        if (RES) val += resp[((long)(m >> 10)) * rowOuter + (long)(m & 1023) * ldc + n];
        if (OUTBF) ((unsigned short*)out)[off] = f2bf(val);
        else       ((float*)out)[off] = val;
      }
    }
  }
}

// ============================ 256x256 kernel =================================
// 512 threads = 8 waves (2 M x 4 N), wave tile 128x64, BK=32, 3 LDS buffers
// (96 KB). Per K-tile: 2 phases; counted vmcnt(4) keeps next tile's loads in
// flight across barriers (never drains in main loop).
template<int BIAS, int RELU, int OUTBF>
__global__ __launch_bounds__(512, 2) void gemm256(
    const unsigned short* __restrict__ A, const unsigned short* __restrict__ Bm,
    const float* __restrict__ bias, void* __restrict__ out,
    int K, int lda, int ldb, int ldc,
    long sA, long sB, long sC1, long rowOuter)
{
  __shared__ unsigned short S[3 * 16384];   // [buf][A:0/B:8192][row*32 + col]
  const int z = blockIdx.z;
  A  += (long)z * sA;
  Bm += (long)z * sB;
  const long outOff = (long)z * sC1;
  const int m0 = blockIdx.x * 256, n0 = blockIdx.y * 256;
  const int tid = threadIdx.x;
  const int lane = tid & 63, wave = tid >> 6;
  const int wr = wave >> 2, wc = wave & 3;        // wave tile: 128 (M) x 64 (N)
  const int fr = lane & 15, kb = lane >> 4;
  const int rr  = tid >> 2;                        // staging row-in-round (0..127)
  const int csw = (((tid & 3) ^ ((tid >> 3) & 3)) << 3);  // pre-swz src col (us)
  const int aco = ((kb ^ ((lane >> 1) & 3)) << 3);         // swz read col (us)
  const int NT = K >> 5;

  fx4 acc[8][4] = {};

  // ---- prologue: stage tiles 0,1 (4 gloads/wave each) ----
  #pragma unroll
  for (int tt = 0; tt < 2; ++tt) {
    #pragma unroll
    for (int r = 0; r < 2; ++r) {
      gload16(A  + (long)(m0 + r * 128 + rr) * lda + tt * 32 + csw,
              &S[tt * 16384 + r * 4096 + wave * 512]);
      gload16(Bm + (long)(n0 + r * 128 + rr) * ldb + tt * 32 + csw,
              &S[tt * 16384 + 8192 + r * 4096 + wave * 512]);
    }
  }
  asm volatile("s_waitcnt vmcnt(4)");   // tile 0 landed; tile 1 in flight
  __builtin_amdgcn_s_barrier();

  for (int t = 0; t < NT; ++t) {
    const int cur = t % 3;
    const int nxt = (t + 2) % 3;
    const int kn = (t + 2) << 5;
    const bool pf = (t + 2) < NT;
    bfx8 af0[4], af1[4], bf[4];

    // ---------- phase 0: stage A(t+2) | read af0,bf | MFMA i=0..3 ----------
    if (pf) {
      gload16(A + (long)(m0 + rr) * lda + kn + csw,       &S[nxt * 16384 + wave * 512]);
      gload16(A + (long)(m0 + 128 + rr) * lda + kn + csw, &S[nxt * 16384 + 4096 + wave * 512]);
    }
    #pragma unroll
    for (int i = 0; i < 4; ++i)
      af0[i] = *reinterpret_cast<const bfx8*>(&S[cur * 16384 + (wr * 128 + i * 16 + fr) * 32 + aco]);
    #pragma unroll
    for (int j = 0; j < 4; ++j)
      bf[j] = *reinterpret_cast<const bfx8*>(&S[cur * 16384 + 8192 + (wc * 64 + j * 16 + fr) * 32 + aco]);
    __builtin_amdgcn_s_barrier();
    asm volatile("s_waitcnt lgkmcnt(0)");
    __builtin_amdgcn_sched_barrier(0);
    __builtin_amdgcn_s_setprio(1);
    #pragma unroll
    for (int i = 0; i < 4; ++i)
      #pragma unroll
      for (int j = 0; j < 4; ++j)
        acc[i][j] = __builtin_amdgcn_mfma_f32_16x16x32_bf16(af0[i], bf[j], acc[i][j], 0, 0, 0);
    __builtin_amdgcn_s_setprio(0);
    __builtin_amdgcn_s_barrier();

    // ---------- phase 1: stage B(t+2) | read af1 | MFMA i=4..7 ----------
    if (pf) {
      gload16(Bm + (long)(n0 + rr) * ldb + kn + csw,       &S[nxt * 16384 + 8192 + wave * 512]);
      gload16(Bm + (long)(n0 + 128 + rr) * ldb + kn + csw, &S[nxt * 16384 + 8192 + 4096 + wave * 512]);
    }
    #pragma unroll
    for (int i = 0; i < 4; ++i)
      af1[i] = *reinterpret_cast<const bfx8*>(&S[cur * 16384 + (wr * 128 + (4 + i) * 16 + fr) * 32 + aco]);
    __builtin_amdgcn_s_barrier();
    asm volatile("s_waitcnt lgkmcnt(0)");
    __builtin_amdgcn_sched_barrier(0);
    __builtin_amdgcn_s_setprio(1);
    #pragma unroll
    for (int i = 0; i < 4; ++i)
      #pragma unroll
      for (int j = 0; j < 4; ++j)
        acc[4 + i][j] = __builtin_amdgcn_mfma_f32_16x16x32_bf16(af1[i], bf[j], acc[4 + i][j], 0, 0, 0);
    __builtin_amdgcn_s_setprio(0);
    __builtin_amdgcn_sched_barrier(0);
    if (pf) asm volatile("s_waitcnt vmcnt(4)");   // tile t+1 landed; t+2 in flight
    else    asm volatile("s_waitcnt vmcnt(0)");
    __builtin_amdgcn_s_barrier();
  }

  const int rbase = (lane >> 4) * 4;
  #pragma unroll
  for (int j = 0; j < 4; ++j) {
    const int n = n0 + wc * 64 + j * 16 + fr;
    float bv = 0.f;
    if (BIAS) bv = bias[n];
    #pragma unroll
    for (int i = 0; i < 8; ++i) {
      #pragma unroll
      for (int r = 0; r < 4; ++r) {
        const int m = m0 + wr * 128 + i * 16 + rbase + r;
        const long off = outOff + ((long)(m >> 10)) * rowOuter + (long)(m & 1023) * ldc + n;
        float val = acc[i][j][r] + bv;
        if (RELU) val = fmaxf(val, 0.f);
        if (OUTBF) ((unsigned short*)out)[off] = f2bf(val);
        else       ((float*)out)[off] = val;
      }
    }
  }
}

// Tiled transpose + convert-to-bf16. src: (batch, R, Cc) TIN; dst: (batch, Cc, R) bf16.
template<typename TIN>
__global__ __launch_bounds__(256) void transpose_k(const TIN* __restrict__ src,
    unsigned short* __restrict__ dst, int R, int Cc) {
  __shared__ float ts[64][65];
  const long zb = blockIdx.z;
  src += zb * (long)R * Cc;
  dst += zb * (long)R * Cc;
  const int r0 = blockIdx.y * 64, c0 = blockIdx.x * 64;
  const int tr = threadIdx.x >> 4;
  const int tc = (threadIdx.x & 15) * 4;
  #pragma unroll
  for (int it = 0; it < 4; ++it) {
    const int r = tr + it * 16;
    float4 v;
    if constexpr (sizeof(TIN) == 4) {
      v = *reinterpret_cast<const float4*>(src + (long)(r0 + r) * Cc + c0 + tc);
    } else {
      usx4 u = *reinterpret_cast<const usx4*>(src + (long)(r0 + r) * Cc + c0 + tc);
      v.x = bf2f(u[0]); v.y = bf2f(u[1]); v.z = bf2f(u[2]); v.w = bf2f(u[3]);
    }
    ts[r][tc + 0] = v.x; ts[r][tc + 1] = v.y; ts[r][tc + 2] = v.z; ts[r][tc + 3] = v.w;
  }
  __syncthreads();
  #pragma unroll
  for (int it = 0; it < 4; ++it) {
    const int cj = tr + it * 16;
    usx4 o = { f2bf(ts[tc + 0][cj]), f2bf(ts[tc + 1][cj]),
               f2bf(ts[tc + 2][cj]), f2bf(ts[tc + 3][cj]) };
    *reinterpret_cast<usx4*>(dst + (long)(c0 + cj) * R + r0 + tc) = o;
  }
}

__global__ __launch_bounds__(256) void embed_k(const int* __restrict__ idx,
                                               const float* __restrict__ tok,
                                               const float* __restrict__ pos,
                                               float* __restrict__ x) {
  const int row = blockIdx.x;
  const int t = row & (T_ - 1);
  const int id = idx[row];
  const int c = threadIdx.x * 4;
  const float4 a = *reinterpret_cast<const float4*>(tok + (long)id * C_ + c);
  const float4 p = *reinterpret_cast<const float4*>(pos + (long)t * C_ + c);
  float4 ov = { a.x + p.x, a.y + p.y, a.z + p.z, a.w + p.w };
  *reinterpret_cast<float4*>(x + (long)row * C_ + c) = ov;
}

// LayerNorm: f32 in, bf16 out.
__global__ __launch_bounds__(256) void ln_k(const float* __restrict__ x,
                                            const float* __restrict__ g,
                                            const float* __restrict__ b,
                                            unsigned short* __restrict__ o) {
  __shared__ float red[8];
  const int row = blockIdx.x;
  const int c = threadIdx.x * 4;
  const float4 v = *reinterpret_cast<const float4*>(x + (long)row * C_ + c);
  float s1 = v.x + v.y + v.z + v.w;
  float s2 = v.x * v.x + v.y * v.y + v.z * v.z + v.w * v.w;
  #pragma unroll
  for (int off = 32; off; off >>= 1) {
    s1 += __shfl_xor(s1, off, 64);
    s2 += __shfl_xor(s2, off, 64);
  }
  const int lane = threadIdx.x & 63, w = threadIdx.x >> 6;
  if (lane == 0) { red[w] = s1; red[4 + w] = s2; }
  __syncthreads();
  s1 = red[0] + red[1] + red[2] + red[3];
  s2 = red[4] + red[5] + red[6] + red[7];
  const float mu = s1 * (1.f / C_);
  float var = s2 * (1.f / C_) - mu * mu;
  var = fmaxf(var, 0.f);
  const float inv = rsqrtf(var + 1e-5f);
  const float4 gg = *reinterpret_cast<const float4*>(g + c);
  const float4 bb = *reinterpret_cast<const float4*>(b + c);
  usx4 ov;
  ov[0] = f2bf((v.x - mu) * inv * gg.x + bb.x);
  ov[1] = f2bf((v.y - mu) * inv * gg.y + bb.y);
  ov[2] = f2bf((v.z - mu) * inv * gg.z + bb.z);
  ov[3] = f2bf((v.w - mu) * inv * gg.w + bb.w);
  *reinterpret_cast<usx4*>(o + (long)row * C_ + c) = ov;
}

// Row softmax on S^T[s][t] (bf16 in), masked to t>=s, scale 1/32; bf16 alphaT out.
__global__ __launch_bounds__(256) void colsm_k(const unsigned short* __restrict__ a,
                                               unsigned short* __restrict__ aT) {
  __shared__ float red[8];
  const int row = blockIdx.x;
  const int s = row & (T_ - 1);
  const unsigned short* p = a + (long)row * T_;
  const int t0 = threadIdx.x * 4;
  const usx4 u = *reinterpret_cast<const usx4*>(p + t0);
  const float scale = 0.03125f;  // 1/sqrt(C)=1/32
  float vals[4];
  float m = -1e30f;
  #pragma unroll
  for (int j = 0; j < 4; ++j) {
    vals[j] = (t0 + j >= s) ? bf2f(u[j]) * scale : -1e30f;
    m = fmaxf(m, vals[j]);
  }
  #pragma unroll
  for (int off = 32; off; off >>= 1) m = fmaxf(m, __shfl_xor(m, off, 64));
  const int lane = threadIdx.x & 63, w = threadIdx.x >> 6;
  if (lane == 0) red[w] = m;
  __syncthreads();
  m = fmaxf(fmaxf(red[0], red[1]), fmaxf(red[2], red[3]));
  __syncthreads();
  float e[4], sum = 0.f;
  #pragma unroll
  for (int j = 0; j < 4; ++j) {
    e[j] = (t0 + j >= s) ? __expf(vals[j] - m) : 0.f;
    sum += e[j];
  }
  #pragma unroll
  for (int off = 32; off; off >>= 1) sum += __shfl_xor(sum, off, 64);
  if (lane == 0) red[w] = sum;
  __syncthreads();
  sum = red[0] + red[1] + red[2] + red[3];
  const float inv = 1.f / sum;
  usx4 ov = { f2bf(e[0] * inv), f2bf(e[1] * inv), f2bf(e[2] * inv), f2bf(e[3] * inv) };
  *reinterpret_cast<usx4*>(aT + (long)row * T_ + t0) = ov;
}

extern "C" void kernel_launch(void* const* d_in, const int* in_sizes, int n_in,
                              void* d_out, int out_size, void* d_ws, size_t ws_size,
                              hipStream_t stream) {
  const int*   idx    = (const int*)d_in[0];
  const float* tok    = (const float*)d_in[1];
  const float* pos    = (const float*)d_in[2];
  const float* wq     = (const float*)d_in[3];
  const float* wk     = (const float*)d_in[4];
  const float* wv     = (const float*)d_in[5];
  const float* proj_w = (const float*)d_in[6];
  const float* proj_b = (const float*)d_in[7];
  const float* ln1_g  = (const float*)d_in[8];
  const float* ln1_b  = (const float*)d_in[9];
  const float* ln2_g  = (const float*)d_in[10];
  const float* ln2_b  = (const float*)d_in[11];
  const float* ff_w1  = (const float*)d_in[12];
  const float* ff_b1  = (const float*)d_in[13];
  const float* ff_w2  = (const float*)d_in[14];
  const float* ff_b2  = (const float*)d_in[15];
  const float* lnf_g  = (const float*)d_in[16];
  const float* lnf_b  = (const float*)d_in[17];
  const float* head_w = (const float*)d_in[18];
  const float* head_b = (const float*)d_in[19];
  float* outp = (float*)d_out;

  typedef unsigned short us;
  char* w = (char*)d_ws;
  float* x    = (float*)(w + 0);            // 16 MB (M,C) f32
  us* xn      = (us*)(w + 16777216);        //  8 MB (M,C)
  us* q       = (us*)(w + 25165824);        //  8 MB (B,H,T,HS)
  us* k       = (us*)(w + 33554432);        //  8 MB
  us* v       = (us*)(w + 41943040);        //  8 MB
  us* vT      = (us*)(w + 50331648);        //  8 MB (B,H,HS,T)
  us* yc      = (us*)(w + 58720256);        //  8 MB (B,T,C)
  us* sc      = (us*)(w + 67108864);        // 32 MB (B*H,T,T) bf16 scores S^T
  us* headT   = (us*)(w + 67108864);        // 64 MB alias (after last colsm/PV)
  us* alpha   = (us*)(w + 100663296);       // 32 MB (B*H,T,T) bf16
  us* aT      = (us*)(w + 134217728);       // 32 MB (B*H,T,T) bf16
  us* hidden  = aT;                         // alias (aT dead after alpha transpose)
  us* wqT     = (us*)(w + 167772160);       //  8 MB (L,H,HS,C)
  us* wkT     = (us*)(w + 176160768);
  us* wvT     = (us*)(w + 184549376);
  us* projT   = (us*)(w + 192937984);       //  8 MB (L,C,C)
  us* ff1T    = (us*)(w + 201326592);       // 32 MB (L,4C,C)
  us* ff2T    = (us*)(w + 234881024);       // 32 MB (L,C,4C)
  if (ws_size < (size_t)268435456) return;  // fail loudly (output stays poisoned)

  // ---- one-time weight transpose + bf16 convert ----
  transpose_k<float><<<dim3(HS_/64, C_/64, L_*H_), 256, 0, stream>>>(wq, wqT, C_, HS_);
  transpose_k<float><<<dim3(HS_/64, C_/64, L_*H_), 256, 0, stream>>>(wk, wkT, C_, HS_);
  transpose_k<float><<<dim3(HS_/64, C_/64, L_*H_), 256, 0, stream>>>(wv, wvT, C_, HS_);
  transpose_k<float><<<dim3(C_/64, C_/64, L_), 256, 0, stream>>>(proj_w, projT, C_, C_);
  transpose_k<float><<<dim3(4*C_/64, C_/64, L_), 256, 0, stream>>>(ff_w1, ff1T, C_, 4*C_);
  transpose_k<float><<<dim3(C_/64, 4*C_/64, L_), 256, 0, stream>>>(ff_w2, ff2T, 4*C_, C_);

  embed_k<<<M_, 256, 0, stream>>>(idx, tok, pos, x);

  for (int l = 0; l < L_; ++l) {
    ln_k<<<M_, 256, 0, stream>>>(x, ln1_g + l * C_, ln1_b + l * C_, xn);

    // q/k/v (B,H,T,HS) bf16
    dim3 gq(M_/128, HS_/128, H_);
    const long wls = (long)H_ * HS_ * C_;
    gemm_bf16<0,0,0,1><<<gq, 256, 0, stream>>>(xn, wqT + l * wls, nullptr, nullptr, q,
        M_, HS_, C_, C_, C_, HS_, 0, (long)HS_*C_, (long)T_*HS_, 0, 0, (long)H_*T_*HS_);
    gemm_bf16<0,0,0,1><<<gq, 256, 0, stream>>>(xn, wkT + l * wls, nullptr, nullptr, k,
        M_, HS_, C_, C_, C_, HS_, 0, (long)HS_*C_, (long)T_*HS_, 0, 0, (long)H_*T_*HS_);
    gemm_bf16<0,0,0,1><<<gq, 256, 0, stream>>>(xn, wvT + l * wls, nullptr, nullptr, v,
        M_, HS_, C_, C_, C_, HS_, 0, (long)HS_*C_, (long)T_*HS_, 0, 0, (long)H_*T_*HS_);

    // S^T[s][t] = sum_d K[s,d]*Q[t,d]  -> bf16 (scale applied in colsm)
    dim3 gs(T_/256, T_/256, B_*H_);
    gemm256<0,0,1><<<gs, 512, 0, stream>>>(k, q, nullptr, sc,
        HS_, HS_, HS_, T_, (long)T_*HS_, (long)T_*HS_, (long)T_*T_, 0);

    // softmax over t (query axis) per (b,h,s) row -> bf16 alphaT
    colsm_k<<<B_*H_*T_, 256, 0, stream>>>(sc, aT);

    // alphaT (s,t) -> alpha (t,s); v (t,d) -> vT (d,t)
    transpose_k<us><<<dim3(T_/64, T_/64, B_*H_), 256, 0, stream>>>(aT, alpha, T_, T_);
    transpose_k<us><<<dim3(HS_/64, T_/64, B_*H_), 256, 0, stream>>>(v, vT, T_, HS_);

    // y[t,d] = sum_s alpha[t,s]*vT[d,s] -> yc (B,T,C) at col h*HS, bf16
    dim3 gp(T_/128, HS_/128, B_*H_);
    gemm_bf16<0,0,0,1><<<gp, 256, 0, stream>>>(alpha, vT, nullptr, nullptr, yc,
        T_, HS_, T_, T_, T_, C_, (long)T_*T_, (long)HS_*T_, (long)T_*C_, HS_, 2, (long)T_*C_);

    // x = x + yc @ proj_w + proj_b   (f32 out)
    dim3 gj(M_/128, C_/128, 1);
    gemm_bf16<1,1,0,0><<<gj, 256, 0, stream>>>(yc, projT + (long)l*C_*C_, proj_b + l*C_, x, x,
        M_, C_, C_, C_, C_, C_, 0, 0, 0, 0, 0, (long)T_*C_);

    ln_k<<<M_, 256, 0, stream>>>(x, ln2_g + l * C_, ln2_b + l * C_, xn);

    // hidden = relu(xn @ ff_w1 + b1)  bf16
    dim3 g1(M_/256, 4*C_/256, 1);
    gemm256<1,1,1><<<g1, 512, 0, stream>>>(xn, ff1T + (long)l*4*C_*C_, ff_b1 + (long)l*4*C_,
        hidden, C_, C_, C_, 4*C_, 0, 0, 0, (long)1024*4*C_);

    // x = x + hidden @ ff_w2 + b2   (f32 out)
    dim3 g2(M_/128, C_/128, 1);
    gemm_bf16<1,1,0,0><<<g2, 256, 0, stream>>>(hidden, ff2T + (long)l*C_*4*C_, ff_b2 + l*C_, x, x,
        M_, C_, 4*C_, 4*C_, 4*C_, C_, 0, 0, 0, 0, 0, (long)T_*C_);
  }

  ln_k<<<M_, 256, 0, stream>>>(x, lnf_g, lnf_b, xn);

  // head weight transpose into the (now dead) scores/alpha region
  transpose_k<float><<<dim3(V_/64, C_/64, 1), 256, 0, stream>>>(head_w, headT, C_, V_);

  dim3 gh(M_/256, V_/256, 1);
  gemm256<1,0,0><<<gh, 512, 0, stream>>>(xn, headT, head_b, outp,
      C_, C_, C_, V_, 0, 0, 0, (long)1024*V_);
}

// Round 5
// 1714.650 us; speedup vs baseline: 3.5442x; 1.0811x over previous
//
#include <hip/hip_runtime.h>

// GPT forward: L=4, H=4, C=1024, HS=256, V=32000, B=4, T=1024. f32 in/out.
// bf16 MFMA 16x16x32. Big GEMMs (head, FF1, QKV-merged, scores): 256x256-tile
// 8-wave 8-phase BK=64 pipeline (half-K-tile slot recycling, counted vmcnt(6),
// XOR swizzle, setprio). Rest: 128x128 m97-structure kernel with swizzle.

#define C_  1024
#define T_  1024
#define HS_ 256
#define H_  4
#define L_  4
#define V_  32000
#define B_  4
#define M_  4096   // B_*T_

typedef __attribute__((ext_vector_type(8))) short  bfx8;
typedef __attribute__((ext_vector_type(4))) float  fx4;
typedef __attribute__((ext_vector_type(4))) unsigned short usx4;

__device__ __forceinline__ unsigned short f2bf(float f) {
  unsigned int u = __builtin_bit_cast(unsigned int, f);
  u += 0x7fffu + ((u >> 16) & 1u);          // round-to-nearest-even
  return (unsigned short)(u >> 16);
}
__device__ __forceinline__ float bf2f(unsigned short u) {
  return __builtin_bit_cast(float, ((unsigned int)u) << 16);
}

// async global->LDS, 16 B per lane. LDS dest = (wave-uniform base) + lane*16.
__device__ __forceinline__ void gload16(const unsigned short* g, unsigned short* l) {
  __builtin_amdgcn_global_load_lds(
      (const __attribute__((address_space(1))) unsigned int*)g,
      (__attribute__((address_space(3))) unsigned int*)l, 16, 0, 0);
}

// ============================ 128x128 kernel =================================
template<int BIAS, int RES, int RELU, int OUTBF>
__global__ __launch_bounds__(256, 2) void gemm_bf16(
    const unsigned short* __restrict__ A, const unsigned short* __restrict__ Bm,
    const float* __restrict__ bias, const float* __restrict__ res,
    void* __restrict__ out,
    int M, int N, int K, int lda, int ldb, int ldc,
    long sA, long sB, long sC1, long sC2, int zShift, long rowOuter)
{
  __shared__ unsigned short As[128 * 32];
  __shared__ unsigned short Bs[128 * 32];
  const int z = blockIdx.z;
  A  += (long)z * sA;
  Bm += (long)z * sB;
  const long outOff = ((long)(z >> zShift)) * sC1 + (long)(z & ((1 << zShift) - 1)) * sC2;
  const int m0 = blockIdx.x * 128, n0 = blockIdx.y * 128;
  const int tid = threadIdx.x;
  const int lane = tid & 63, wave = tid >> 6;
  const int wm = (wave >> 1) * 64, wn = (wave & 1) * 64;
  const int fr = lane & 15, kb = lane >> 4;
  const int sr = lane >> 2;
  const int csw = (((lane & 3) ^ ((lane >> 3) & 3)) << 3);
  const int aco = ((kb ^ ((lane >> 1) & 3)) << 3);

  fx4 acc[4][4] = {};

  for (int k0 = 0; k0 < K; k0 += 32) {
    #pragma unroll
    for (int i = 0; i < 2; ++i) {
      const int c = wave * 2 + i;
      gload16(A  + (long)(m0 + c * 16 + sr) * lda + k0 + csw, &As[c * 512]);
      gload16(Bm + (long)(n0 + c * 16 + sr) * ldb + k0 + csw, &Bs[c * 512]);
    }
    __syncthreads();
    bfx8 af[4], bf[4];
    #pragma unroll
    for (int i = 0; i < 4; ++i)
      af[i] = *reinterpret_cast<const bfx8*>(&As[(wm + i * 16 + fr) * 32 + aco]);
    #pragma unroll
    for (int j = 0; j < 4; ++j)
      bf[j] = *reinterpret_cast<const bfx8*>(&Bs[(wn + j * 16 + fr) * 32 + aco]);
    #pragma unroll
    for (int i = 0; i < 4; ++i)
      #pragma unroll
      for (int j = 0; j < 4; ++j)
        acc[i][j] = __builtin_amdgcn_mfma_f32_16x16x32_bf16(af[i], bf[j], acc[i][j], 0, 0, 0);
    __syncthreads();
  }

  const float* resp = res;
  if (RES) resp += outOff;
  const int rbase = (lane >> 4) * 4;
  #pragma unroll
  for (int j = 0; j < 4; ++j) {
    const int n = n0 + wn + j * 16 + fr;
    float bv = 0.f;
    if (BIAS) bv = bias[n];
    #pragma unroll
    for (int i = 0; i < 4; ++i) {
      #pragma unroll
      for (int r = 0; r < 4; ++r) {
        const int m = m0 + wm + i * 16 + rbase + r;
        const long off = outOff + ((long)(m >> 10)) * rowOuter + (long)(m & 1023) * ldc + n;
        float val = acc[i][j][r] + bv;
        if (RELU) val = fmaxf(val, 0.f);
        if (RES) val += resp[((long)(m >> 10)) * rowOuter + (long)(m & 1023) * ldc + n];
        if (OUTBF) ((unsigned short*)out)[off] = f2bf(val);
        else       ((float*)out)[off] = val;
      }
    }
  }
}

// ============================ 256x256 8-phase kernel =========================
// 512 thr = 8 waves (2M x 4N), wave tile 128x64, BK=64 (2 ksteps of 32).
// LDS: 8 slots [256 rows][32 K] bf16: A[p][kh] @ (p*2+kh)*8192, B @ +32768.
// Slot consumed over 2 phases (both rowhalves of one kstep) then re-staged.
// 1 half-tile (2 gloads) staged per phase; vmcnt(6) at even phases.
#define BAR() __builtin_amdgcn_s_barrier()
#define LGKM() { asm volatile("s_waitcnt lgkmcnt(0)" ::: "memory"); \
                 __builtin_amdgcn_sched_barrier(0); }
#define VM6()  asm volatile("s_waitcnt vmcnt(6)" ::: "memory")
#define RD_A(p, kh, rh) { _Pragma("unroll") for (int i = 0; i < 4; ++i) \
  af[i] = *reinterpret_cast<const bfx8*>(&S[((p)*2+(kh))*8192 + (wr*128 + (rh)*64 + i*16 + fr)*32 + aco]); }
#define RD_B(p, kh) { _Pragma("unroll") for (int j = 0; j < 4; ++j) \
  bf[j] = *reinterpret_cast<const bfx8*>(&S[32768 + ((p)*2+(kh))*8192 + (wc*64 + j*16 + fr)*32 + aco]); }
#define MM16(rh) { __builtin_amdgcn_s_setprio(1); \
  _Pragma("unroll") for (int i = 0; i < 4; ++i) { _Pragma("unroll") for (int j = 0; j < 4; ++j) \
    acc[(rh)*4+i][j] = __builtin_amdgcn_mfma_f32_16x16x32_bf16(af[i], bf[j], acc[(rh)*4+i][j], 0, 0, 0); } \
  __builtin_amdgcn_s_setprio(0); }

template<int BIAS, int RELU, int OUTBF, int EPI>
__global__ __launch_bounds__(512, 2) void gemm256(
    const unsigned short* __restrict__ A, const unsigned short* __restrict__ Bm,
    const float* __restrict__ bias, void* __restrict__ out,
    int K, int lda, int ldb, int ldc,
    long sA, long sB, long sC1, long rowOuter)
{
  __shared__ unsigned short S[65536];   // 128 KB
  const int z = blockIdx.z;
  A  += (long)z * sA;
  Bm += (long)z * sB;
  const long outOff = (long)z * sC1;
  const int m0 = blockIdx.x * 256, n0 = blockIdx.y * 256;
  const int tid = threadIdx.x;
  const int lane = tid & 63, wave = tid >> 6;
  const int wr = wave >> 2, wc = wave & 3;
  const int fr = lane & 15, kb = lane >> 4;
  const int srow = lane >> 2;
  const int csw = (((lane & 3) ^ ((lane >> 2) & 3)) << 3);  // pre-swz source col (us)
  const int aco = ((kb ^ (fr & 3)) << 3);                   // swz read col (us)
  const int NT = K >> 6;    // K-tiles of 64 (even NT assumed)
  const int NI = NT >> 1;

  fx4 acc[8][4] = {};
  bfx8 af[4], bf[4];

  auto stA = [&](int tau, int kh) {
    const int tc = tau < NT ? tau : NT - 1;
    const unsigned short* src = A + (long)(m0 + wave * 16 + srow) * lda + tc * 64 + kh * 32 + csw;
    unsigned short* d = &S[((tau & 1) * 2 + kh) * 8192 + wave * 512];
    gload16(src, d);
    gload16(src + (long)128 * lda, d + 4096);
  };
  auto stB = [&](int tau, int kh) {
    const int tc = tau < NT ? tau : NT - 1;
    const unsigned short* src = Bm + (long)(n0 + wave * 16 + srow) * ldb + tc * 64 + kh * 32 + csw;
    unsigned short* d = &S[32768 + ((tau & 1) * 2 + kh) * 8192 + wave * 512];
    gload16(src, d);
    gload16(src + (long)128 * ldb, d + 4096);
  };

  // prologue: K-tile 0 (both khalves) + K-tile 1 khalf0  (6 half-tiles)
  stA(0, 0); stB(0, 0); stA(0, 1); stB(0, 1); stA(1, 0); stB(1, 0);
  asm volatile("s_waitcnt vmcnt(8)" ::: "memory");   // K-tile 0 khalf0 landed
  BAR();

  for (int t = 0; t < NI; ++t) {
    const int u = 2 * t;
    // ph1: ktile u, kstep0, rows 0-63        | stage A(u+1, k1)
    RD_A(0, 0, 0); RD_B(0, 0); stA(u + 1, 1);
    BAR(); LGKM(); MM16(0); BAR();
    // ph2: ktile u, kstep0, rows 64-127      | stage B(u+1, k1)
    RD_A(0, 0, 1); stB(u + 1, 1);
    BAR(); LGKM(); MM16(1); VM6(); BAR();
    // ph3: ktile u, kstep1, rows 0-63        | stage A(u+2, k0)
    RD_A(0, 1, 0); RD_B(0, 1); stA(u + 2, 0);
    BAR(); LGKM(); MM16(0); BAR();
    // ph4: ktile u, kstep1, rows 64-127      | stage B(u+2, k0)
    RD_A(0, 1, 1); stB(u + 2, 0);
    BAR(); LGKM(); MM16(1); VM6(); BAR();
    // ph5: ktile u+1, kstep0, rows 0-63      | stage A(u+2, k1)
    RD_A(1, 0, 0); RD_B(1, 0); stA(u + 2, 1);
    BAR(); LGKM(); MM16(0); BAR();
    // ph6: ktile u+1, kstep0, rows 64-127    | stage B(u+2, k1)
    RD_A(1, 0, 1); stB(u + 2, 1);
    BAR(); LGKM(); MM16(1); VM6(); BAR();
    // ph7: ktile u+1, kstep1, rows 0-63      | stage A(u+3, k0)
    RD_A(1, 1, 0); RD_B(1, 1); stA(u + 3, 0);
    BAR(); LGKM(); MM16(0); BAR();
    // ph8: ktile u+1, kstep1, rows 64-127    | stage B(u+3, k0)
    RD_A(1, 1, 1); stB(u + 3, 0);
    BAR(); LGKM(); MM16(1); VM6(); BAR();
  }
  asm volatile("s_waitcnt vmcnt(0)" ::: "memory");  // drain dangling prefetches

  const int rbase = (lane >> 4) * 4;
  if (EPI == 1) {
    // QKV scatter: n0 block-constant -> sel (q/k/v), head h. d = n & 255.
    const int sel = n0 >> 10, h = (n0 >> 8) & 3;
    unsigned short* dst = (unsigned short*)out
        + (long)sel * ((long)B_ * H_ * T_ * HS_) + (long)h * T_ * HS_;
    #pragma unroll
    for (int j = 0; j < 4; ++j) {
      const int d = wc * 64 + j * 16 + fr;
      #pragma unroll
      for (int i = 0; i < 8; ++i) {
        #pragma unroll
        for (int r = 0; r < 4; ++r) {
          const int m = m0 + wr * 128 + i * 16 + rbase + r;
          const int bq = m >> 10, tq = m & 1023;
          dst[(long)bq * H_ * T_ * HS_ + (long)tq * HS_ + d] = f2bf(acc[i][j][r]);
        }
      }
    }
  } else {
    #pragma unroll
    for (int j = 0; j < 4; ++j) {
      const int n = n0 + wc * 64 + j * 16 + fr;
      float bv = 0.f;
      if (BIAS) bv = bias[n];
      #pragma unroll
      for (int i = 0; i < 8; ++i) {
        #pragma unroll
        for (int r = 0; r < 4; ++r) {
          const int m = m0 + wr * 128 + i * 16 + rbase + r;
          const long off = outOff + ((long)(m >> 10)) * rowOuter + (long)(m & 1023) * ldc + n;
          float val = acc[i][j][r] + bv;
          if (RELU) val = fmaxf(val, 0.f);
          if (OUTBF) ((unsigned short*)out)[off] = f2bf(val);
          else       ((float*)out)[off] = val;
        }
      }
    }
  }
}

// Tiled transpose + convert-to-bf16. src: (batch zb, R, Cc) TIN;
// dst base: dst + (zb>>zShiftT)*sOuter + (zb&mask)*(R*Cc); writes (Cc,R) bf16.
template<typename TIN>
__global__ __launch_bounds__(256) void transpose_k(const TIN* __restrict__ src,
    unsigned short* __restrict__ dst, int R, int Cc, int zShiftT, long sOuter) {
  __shared__ float ts[64][65];
  const long zb = blockIdx.z;
  src += zb * (long)R * Cc;
  dst += (zb >> zShiftT) * sOuter + (zb & ((1 << zShiftT) - 1)) * ((long)R * Cc);
  const int r0 = blockIdx.y * 64, c0 = blockIdx.x * 64;
  const int tr = threadIdx.x >> 4;
  const int tc = (threadIdx.x & 15) * 4;
  #pragma unroll
  for (int it = 0; it < 4; ++it) {
    const int r = tr + it * 16;
    float4 v;
    if constexpr (sizeof(TIN) == 4) {
      v = *reinterpret_cast<const float4*>(src + (long)(r0 + r) * Cc + c0 + tc);
    } else {
      usx4 u = *reinterpret_cast<const usx4*>(src + (long)(r0 + r) * Cc + c0 + tc);
      v.x = bf2f(u[0]); v.y = bf2f(u[1]); v.z = bf2f(u[2]); v.w = bf2f(u[3]);
    }
    ts[r][tc + 0] = v.x; ts[r][tc + 1] = v.y; ts[r][tc + 2] = v.z; ts[r][tc + 3] = v.w;
  }
  __syncthreads();
  #pragma unroll
  for (int it = 0; it < 4; ++it) {
    const int cj = tr + it * 16;
    usx4 o = { f2bf(ts[tc + 0][cj]), f2bf(ts[tc + 1][cj]),
               f2bf(ts[tc + 2][cj]), f2bf(ts[tc + 3][cj]) };
    *reinterpret_cast<usx4*>(dst + (long)(c0 + cj) * R + r0 + tc) = o;
  }
}

__global__ __launch_bounds__(256) void embed_k(const int* __restrict__ idx,
                                               const float* __restrict__ tok,
                                               const float* __restrict__ pos,
                                               float* __restrict__ x) {
  const int row = blockIdx.x;
  const int t = row & (T_ - 1);
  const int id = idx[row];
  const int c = threadIdx.x * 4;
  const float4 a = *reinterpret_cast<const float4*>(tok + (long)id * C_ + c);
  const float4 p = *reinterpret_cast<const float4*>(pos + (long)t * C_ + c);
  float4 ov = { a.x + p.x, a.y + p.y, a.z + p.z, a.w + p.w };
  *reinterpret_cast<float4*>(x + (long)row * C_ + c) = ov;
}

// LayerNorm: f32 in, bf16 out.
__global__ __launch_bounds__(256) void ln_k(const float* __restrict__ x,
                                            const float* __restrict__ g,
                                            const float* __restrict__ b,
                                            unsigned short* __restrict__ o) {
  __shared__ float red[8];
  const int row = blockIdx.x;
  const int c = threadIdx.x * 4;
  const float4 v = *reinterpret_cast<const float4*>(x + (long)row * C_ + c);
  float s1 = v.x + v.y + v.z + v.w;
  float s2 = v.x * v.x + v.y * v.y + v.z * v.z + v.w * v.w;
  #pragma unroll
  for (int off = 32; off; off >>= 1) {
    s1 += __shfl_xor(s1, off, 64);
    s2 += __shfl_xor(s2, off, 64);
  }
  const int lane = threadIdx.x & 63, w = threadIdx.x >> 6;
  if (lane == 0) { red[w] = s1; red[4 + w] = s2; }
  __syncthreads();
  s1 = red[0] + red[1] + red[2] + red[3];
  s2 = red[4] + red[5] + red[6] + red[7];
  const float mu = s1 * (1.f / C_);
  float var = s2 * (1.f / C_) - mu * mu;
  var = fmaxf(var, 0.f);
  const float inv = rsqrtf(var + 1e-5f);
  const float4 gg = *reinterpret_cast<const float4*>(g + c);
  const float4 bb = *reinterpret_cast<const float4*>(b + c);
  usx4 ov;
  ov[0] = f2bf((v.x - mu) * inv * gg.x + bb.x);
  ov[1] = f2bf((v.y - mu) * inv * gg.y + bb.y);
  ov[2] = f2bf((v.z - mu) * inv * gg.z + bb.z);
  ov[3] = f2bf((v.w - mu) * inv * gg.w + bb.w);
  *reinterpret_cast<usx4*>(o + (long)row * C_ + c) = ov;
}

// Row softmax on S^T[s][t] (bf16), masked to t>=s, scale 1/32; bf16 alphaT out.
__global__ __launch_bounds__(256) void colsm_k(const unsigned short* __restrict__ a,
                                               unsigned short* __restrict__ aT) {
  __shared__ float red[8];
  const int row = blockIdx.x;
  const int s = row & (T_ - 1);
  const unsigned short* p = a + (long)row * T_;
  const int t0 = threadIdx.x * 4;
  const usx4 u = *reinterpret_cast<const usx4*>(p + t0);
  const float scale = 0.03125f;  // 1/sqrt(C)=1/32
  float vals[4];
  float m = -1e30f;
  #pragma unroll
  for (int j = 0; j < 4; ++j) {
    vals[j] = (t0 + j >= s) ? bf2f(u[j]) * scale : -1e30f;
    m = fmaxf(m, vals[j]);
  }
  #pragma unroll
  for (int off = 32; off; off >>= 1) m = fmaxf(m, __shfl_xor(m, off, 64));
  const int lane = threadIdx.x & 63, w = threadIdx.x >> 6;
  if (lane == 0) red[w] = m;
  __syncthreads();
  m = fmaxf(fmaxf(red[0], red[1]), fmaxf(red[2], red[3]));
  __syncthreads();
  float e[4], sum = 0.f;
  #pragma unroll
  for (int j = 0; j < 4; ++j) {
    e[j] = (t0 + j >= s) ? __expf(vals[j] - m) : 0.f;
    sum += e[j];
  }
  #pragma unroll
  for (int off = 32; off; off >>= 1) sum += __shfl_xor(sum, off, 64);
  if (lane == 0) red[w] = sum;
  __syncthreads();
  sum = red[0] + red[1] + red[2] + red[3];
  const float inv = 1.f / sum;
  usx4 ov = { f2bf(e[0] * inv), f2bf(e[1] * inv), f2bf(e[2] * inv), f2bf(e[3] * inv) };
  *reinterpret_cast<usx4*>(aT + (long)row * T_ + t0) = ov;
}

extern "C" void kernel_launch(void* const* d_in, const int* in_sizes, int n_in,
                              void* d_out, int out_size, void* d_ws, size_t ws_size,
                              hipStream_t stream) {
  const int*   idx    = (const int*)d_in[0];
  const float* tok    = (const float*)d_in[1];
  const float* pos    = (const float*)d_in[2];
  const float* wq     = (const float*)d_in[3];
  const float* wk     = (const float*)d_in[4];
  const float* wv     = (const float*)d_in[5];
  const float* proj_w = (const float*)d_in[6];
  const float* proj_b = (const float*)d_in[7];
  const float* ln1_g  = (const float*)d_in[8];
  const float* ln1_b  = (const float*)d_in[9];
  const float* ln2_g  = (const float*)d_in[10];
  const float* ln2_b  = (const float*)d_in[11];
  const float* ff_w1  = (const float*)d_in[12];
  const float* ff_b1  = (const float*)d_in[13];
  const float* ff_w2  = (const float*)d_in[14];
  const float* ff_b2  = (const float*)d_in[15];
  const float* lnf_g  = (const float*)d_in[16];
  const float* lnf_b  = (const float*)d_in[17];
  const float* head_w = (const float*)d_in[18];
  const float* head_b = (const float*)d_in[19];
  float* outp = (float*)d_out;

  typedef unsigned short us;
  char* w = (char*)d_ws;
  float* x    = (float*)(w + 0);            // 16 MB (M,C) f32
  us* xn      = (us*)(w + 16777216);        //  8 MB (M,C)
  us* qkv     = (us*)(w + 25165824);        // 24 MB: q,k,v each (B,H,T,HS)
  us* kptr    = qkv + 4194304;
  us* vptr    = qkv + 8388608;
  us* vT      = (us*)(w + 50331648);        //  8 MB (B,H,HS,T)
  us* yc      = (us*)(w + 58720256);        //  8 MB (B,T,C)
  us* sc      = (us*)(w + 67108864);        // 32 MB (B*H,T,T) scores S^T
  us* headT   = (us*)(w + 67108864);        // 65.5 MB alias over sc+alpha
  us* alpha   = (us*)(w + 100663296);       // 32 MB (B*H,T,T)
  us* aT      = (us*)(w + 134217728);       // 32 MB (B*H,T,T)
  us* hidden  = aT;                         // alias (aT dead after transpose)
  us* wqkvT   = (us*)(w + 167772160);       // 24 MB (L,3,H,HS,C)
  us* projT   = (us*)(w + 192937984);       //  8 MB (L,C,C)
  us* ff1T    = (us*)(w + 201326592);       // 32 MB (L,4C,C)
  us* ff2T    = (us*)(w + 234881024);       // 32 MB (L,C,4C)
  if (ws_size < (size_t)268435456) return;  // fail loudly

  const long HHC = (long)H_ * HS_ * C_;     // per-matrix per-layer us
  // ---- one-time weight transpose + bf16 convert ----
  transpose_k<float><<<dim3(HS_/64, C_/64, L_*H_), 256, 0, stream>>>(wq, wqkvT,           C_, HS_, 2, 3*HHC);
  transpose_k<float><<<dim3(HS_/64, C_/64, L_*H_), 256, 0, stream>>>(wk, wqkvT + HHC,     C_, HS_, 2, 3*HHC);
  transpose_k<float><<<dim3(HS_/64, C_/64, L_*H_), 256, 0, stream>>>(wv, wqkvT + 2*HHC,   C_, HS_, 2, 3*HHC);
  transpose_k<float><<<dim3(C_/64, C_/64, L_), 256, 0, stream>>>(proj_w, projT, C_, C_, 0, (long)C_*C_);
  transpose_k<float><<<dim3(4*C_/64, C_/64, L_), 256, 0, stream>>>(ff_w1, ff1T, C_, 4*C_, 0, (long)C_*4*C_);
  transpose_k<float><<<dim3(C_/64, 4*C_/64, L_), 256, 0, stream>>>(ff_w2, ff2T, 4*C_, C_, 0, (long)4*C_*C_);

  embed_k<<<M_, 256, 0, stream>>>(idx, tok, pos, x);

  for (int l = 0; l < L_; ++l) {
    ln_k<<<M_, 256, 0, stream>>>(x, ln1_g + l * C_, ln1_b + l * C_, xn);

    // merged QKV: N=3072 (sel,h,d) scatter epilogue -> qkv (3,B,H,T,HS)
    dim3 gqkv(M_/256, 3*C_/256, 1);
    gemm256<0,0,1,1><<<gqkv, 512, 0, stream>>>(xn, wqkvT + l * 3 * HHC, nullptr, qkv,
        C_, C_, C_, 0, 0, 0, 0, 0);

    // S^T[s][t] = sum_d K[s,d]*Q[t,d]  -> bf16 (scale applied in colsm)
    dim3 gs(T_/256, T_/256, B_*H_);
    gemm256<0,0,1,0><<<gs, 512, 0, stream>>>(kptr, qkv, nullptr, sc,
        HS_, HS_, HS_, T_, (long)T_*HS_, (long)T_*HS_, (long)T_*T_, 0);

    // softmax over t (query axis) per (b,h,s) row -> bf16 alphaT
    colsm_k<<<B_*H_*T_, 256, 0, stream>>>(sc, aT);

    // alphaT (s,t) -> alpha (t,s); v (t,d) -> vT (d,t)
    transpose_k<us><<<dim3(T_/64, T_/64, B_*H_), 256, 0, stream>>>(aT, alpha, T_, T_, 0, (long)T_*T_);
    transpose_k<us><<<dim3(HS_/64, T_/64, B_*H_), 256, 0, stream>>>(vptr, vT, T_, HS_, 0, (long)T_*HS_);

    // y[t,d] = sum_s alpha[t,s]*vT[d,s] -> yc (B,T,C) at col h*HS, bf16
    dim3 gp(T_/128, HS_/128, B_*H_);
    gemm_bf16<0,0,0,1><<<gp, 256, 0, stream>>>(alpha, vT, nullptr, nullptr, yc,
        T_, HS_, T_, T_, T_, C_, (long)T_*T_, (long)HS_*T_, (long)T_*C_, HS_, 2, (long)T_*C_);

    // x = x + yc @ proj_w + proj_b   (f32 out)
    dim3 gj(M_/128, C_/128, 1);
    gemm_bf16<1,1,0,0><<<gj, 256, 0, stream>>>(yc, projT + (long)l*C_*C_, proj_b + l*C_, x, x,
        M_, C_, C_, C_, C_, C_, 0, 0, 0, 0, 0, (long)T_*C_);

    ln_k<<<M_, 256, 0, stream>>>(x, ln2_g + l * C_, ln2_b + l * C_, xn);

    // hidden = relu(xn @ ff_w1 + b1)  bf16
    dim3 g1(M_/256, 4*C_/256, 1);
    gemm256<1,1,1,0><<<g1, 512, 0, stream>>>(xn, ff1T + (long)l*4*C_*C_, ff_b1 + (long)l*4*C_,
        hidden, C_, C_, C_, 4*C_, 0, 0, 0, (long)1024*4*C_);

    // x = x + hidden @ ff_w2 + b2   (f32 out)
    dim3 g2(M_/128, C_/128, 1);
    gemm_bf16<1,1,0,0><<<g2, 256, 0, stream>>>(hidden, ff2T + (long)l*C_*4*C_, ff_b2 + l*C_, x, x,
        M_, C_, 4*C_, 4*C_, 4*C_, C_, 0, 0, 0, 0, 0, (long)T_*C_);
  }

  ln_k<<<M_, 256, 0, stream>>>(x, lnf_g, lnf_b, xn);

  // head weight transpose into the (now dead) scores/alpha region
  transpose_k<float><<<dim3(V_/64, C_/64, 1), 256, 0, stream>>>(head_w, headT, C_, V_, 0, (long)C_*V_);

  dim3 gh(M_/256, V_/256, 1);
  gemm256<1,0,0,0><<<gh, 512, 0, stream>>>(xn, headT, head_b, outp,
      C_, C_, C_, V_, 0, 0, 0, (long)1024*V_);
}

// Round 6
// 1609.509 us; speedup vs baseline: 3.7758x; 1.0653x over previous
//
#include <hip/hip_runtime.h>

// GPT forward: L=4, H=4, C=1024, HS=256, V=32000, B=4, T=1024. f32 in/out.
// bf16 MFMA 16x16x32. Big GEMMs (head, FF1, QKV-merged, scores): 256x256-tile
// 8-wave 8-phase BK=64 pipeline (st_16x32 swizzle, counted vmcnt(6), setprio,
// LDS-transposed coalesced epilogue). Rest: 128x128 m97-structure kernel.

#define C_  1024
#define T_  1024
#define HS_ 256
#define H_  4
#define L_  4
#define V_  32000
#define B_  4
#define M_  4096   // B_*T_

typedef __attribute__((ext_vector_type(8))) short  bfx8;
typedef __attribute__((ext_vector_type(4))) float  fx4;
typedef __attribute__((ext_vector_type(4))) unsigned short usx4;

__device__ __forceinline__ unsigned short f2bf(float f) {
  unsigned int u = __builtin_bit_cast(unsigned int, f);
  u += 0x7fffu + ((u >> 16) & 1u);          // round-to-nearest-even
  return (unsigned short)(u >> 16);
}
__device__ __forceinline__ float bf2f(unsigned short u) {
  return __builtin_bit_cast(float, ((unsigned int)u) << 16);
}

// async global->LDS, 16 B per lane. LDS dest = (wave-uniform base) + lane*16.
__device__ __forceinline__ void gload16(const unsigned short* g, unsigned short* l) {
  __builtin_amdgcn_global_load_lds(
      (const __attribute__((address_space(1))) unsigned int*)g,
      (__attribute__((address_space(3))) unsigned int*)l, 16, 0, 0);
}

// ============================ 128x128 kernel =================================
template<int BIAS, int RES, int RELU, int OUTBF>
__global__ __launch_bounds__(256, 2) void gemm_bf16(
    const unsigned short* __restrict__ A, const unsigned short* __restrict__ Bm,
    const float* __restrict__ bias, const float* __restrict__ res,
    void* __restrict__ out,
    int M, int N, int K, int lda, int ldb, int ldc,
    long sA, long sB, long sC1, long sC2, int zShift, long rowOuter)
{
  __shared__ unsigned short As[128 * 32];
  __shared__ unsigned short Bs[128 * 32];
  const int z = blockIdx.z;
  A  += (long)z * sA;
  Bm += (long)z * sB;
  const long outOff = ((long)(z >> zShift)) * sC1 + (long)(z & ((1 << zShift) - 1)) * sC2;
  const int m0 = blockIdx.x * 128, n0 = blockIdx.y * 128;
  const int tid = threadIdx.x;
  const int lane = tid & 63, wave = tid >> 6;
  const int wm = (wave >> 1) * 64, wn = (wave & 1) * 64;
  const int fr = lane & 15, kb = lane >> 4;
  const int sr = lane >> 2;
  const int csw = (((lane & 3) ^ ((lane >> 3) & 3)) << 3);
  const int aco = ((kb ^ ((lane >> 1) & 3)) << 3);

  fx4 acc[4][4] = {};

  for (int k0 = 0; k0 < K; k0 += 32) {
    #pragma unroll
    for (int i = 0; i < 2; ++i) {
      const int c = wave * 2 + i;
      gload16(A  + (long)(m0 + c * 16 + sr) * lda + k0 + csw, &As[c * 512]);
      gload16(Bm + (long)(n0 + c * 16 + sr) * ldb + k0 + csw, &Bs[c * 512]);
    }
    __syncthreads();
    bfx8 af[4], bf[4];
    #pragma unroll
    for (int i = 0; i < 4; ++i)
      af[i] = *reinterpret_cast<const bfx8*>(&As[(wm + i * 16 + fr) * 32 + aco]);
    #pragma unroll
    for (int j = 0; j < 4; ++j)
      bf[j] = *reinterpret_cast<const bfx8*>(&Bs[(wn + j * 16 + fr) * 32 + aco]);
    #pragma unroll
    for (int i = 0; i < 4; ++i)
      #pragma unroll
      for (int j = 0; j < 4; ++j)
        acc[i][j] = __builtin_amdgcn_mfma_f32_16x16x32_bf16(af[i], bf[j], acc[i][j], 0, 0, 0);
    __syncthreads();
  }

  const float* resp = res;
  if (RES) resp += outOff;
  const int rbase = (lane >> 4) * 4;
  #pragma unroll
  for (int j = 0; j < 4; ++j) {
    const int n = n0 + wn + j * 16 + fr;
    float bv = 0.f;
    if (BIAS) bv = bias[n];
    #pragma unroll
    for (int i = 0; i < 4; ++i) {
      #pragma unroll
      for (int r = 0; r < 4; ++r) {
        const int m = m0 + wm + i * 16 + rbase + r;
        const long off = outOff + ((long)(m >> 10)) * rowOuter + (long)(m & 1023) * ldc + n;
        float val = acc[i][j][r] + bv;
        if (RELU) val = fmaxf(val, 0.f);
        if (RES) val += resp[((long)(m >> 10)) * rowOuter + (long)(m & 1023) * ldc + n];
        if (OUTBF) ((unsigned short*)out)[off] = f2bf(val);
        else       ((float*)out)[off] = val;
      }
    }
  }
}

// ============================ 256x256 8-phase kernel =========================
// 512 thr = 8 waves (2M x 4N), wave tile 128x64, BK=64 (2 ksteps of 32).
// LDS: 8 slots [256 rows][32 K] bf16; st_16x32 swizzle (m201-verified):
// 16B slot-in-row ^= ((row&15)>>3)<<1, via pre-swizzled global source.
#define BAR() __builtin_amdgcn_s_barrier()
#define LGKM() { asm volatile("s_waitcnt lgkmcnt(0)" ::: "memory"); \
                 __builtin_amdgcn_sched_barrier(0); }
#define VM6()  asm volatile("s_waitcnt vmcnt(6)" ::: "memory")
#define RD_A(p, kh, rh) { _Pragma("unroll") for (int i = 0; i < 4; ++i) \
  af[i] = *reinterpret_cast<const bfx8*>(&S[((p)*2+(kh))*8192 + (wr*128 + (rh)*64 + i*16 + fr)*32 + aco]); }
#define RD_B(p, kh) { _Pragma("unroll") for (int j = 0; j < 4; ++j) \
  bf[j] = *reinterpret_cast<const bfx8*>(&S[32768 + ((p)*2+(kh))*8192 + (wc*64 + j*16 + fr)*32 + aco]); }
#define MM16(rh) { __builtin_amdgcn_s_setprio(1); \
  _Pragma("unroll") for (int i = 0; i < 4; ++i) { _Pragma("unroll") for (int j = 0; j < 4; ++j) \
    acc[(rh)*4+i][j] = __builtin_amdgcn_mfma_f32_16x16x32_bf16(af[i], bf[j], acc[(rh)*4+i][j], 0, 0, 0); } \
  __builtin_amdgcn_s_setprio(0); }

template<int BIAS, int RELU, int OUTBF, int EPI>
__global__ __launch_bounds__(512, 2) void gemm256(
    const unsigned short* __restrict__ A, const unsigned short* __restrict__ Bm,
    const float* __restrict__ bias, void* __restrict__ out,
    int K, int lda, int ldb, int ldc,
    long sA, long sB, long sC1, long rowOuter)
{
  __shared__ unsigned short S[65536];   // 128 KB
  const int z = blockIdx.z;
  A  += (long)z * sA;
  Bm += (long)z * sB;
  const long outOff = (long)z * sC1;
  const int m0 = blockIdx.x * 256, n0 = blockIdx.y * 256;
  const int tid = threadIdx.x;
  const int lane = tid & 63, wave = tid >> 6;
  const int wr = wave >> 2, wc = wave & 3;
  const int fr = lane & 15, kb = lane >> 4;
  const int srow = lane >> 2;
  // st_16x32: slot-in-row ^= ((row&15)>>3)<<1. srow = row&15 on staging;
  // fr = row&15 on fragment read.
  const int csw = (((lane & 3) ^ (((lane >> 5) & 1) << 1)) << 3);
  const int aco = ((kb ^ (((fr >> 3) & 1) << 1)) << 3);
  const int NT = K >> 6;    // K-tiles of 64 (even NT assumed)
  const int NI = NT >> 1;

  fx4 acc[8][4] = {};
  bfx8 af[4], bf[4];

  auto stA = [&](int tau, int kh) {
    const int tc = tau < NT ? tau : NT - 1;
    const unsigned short* src = A + (long)(m0 + wave * 16 + srow) * lda + tc * 64 + kh * 32 + csw;
    unsigned short* d = &S[((tau & 1) * 2 + kh) * 8192 + wave * 512];
    gload16(src, d);
    gload16(src + (long)128 * lda, d + 4096);
  };
  auto stB = [&](int tau, int kh) {
    const int tc = tau < NT ? tau : NT - 1;
    const unsigned short* src = Bm + (long)(n0 + wave * 16 + srow) * ldb + tc * 64 + kh * 32 + csw;
    unsigned short* d = &S[32768 + ((tau & 1) * 2 + kh) * 8192 + wave * 512];
    gload16(src, d);
    gload16(src + (long)128 * ldb, d + 4096);
  };

  // prologue: K-tile 0 (both khalves) + K-tile 1 khalf0  (6 half-tiles)
  stA(0, 0); stB(0, 0); stA(0, 1); stB(0, 1); stA(1, 0); stB(1, 0);
  asm volatile("s_waitcnt vmcnt(8)" ::: "memory");   // K-tile 0 khalf0 landed
  BAR();

  for (int t = 0; t < NI; ++t) {
    const int u = 2 * t;
    // ph1: ktile u, kstep0, rows 0-63        | stage A(u+1, k1)
    RD_A(0, 0, 0); RD_B(0, 0); stA(u + 1, 1);
    BAR(); LGKM(); MM16(0); BAR();
    // ph2: ktile u, kstep0, rows 64-127      | stage B(u+1, k1)
    RD_A(0, 0, 1); stB(u + 1, 1);
    BAR(); LGKM(); MM16(1); VM6(); BAR();
    // ph3: ktile u, kstep1, rows 0-63        | stage A(u+2, k0)
    RD_A(0, 1, 0); RD_B(0, 1); stA(u + 2, 0);
    BAR(); LGKM(); MM16(0); BAR();
    // ph4: ktile u, kstep1, rows 64-127      | stage B(u+2, k0)
    RD_A(0, 1, 1); stB(u + 2, 0);
    BAR(); LGKM(); MM16(1); VM6(); BAR();
    // ph5: ktile u+1, kstep0, rows 0-63      | stage A(u+2, k1)
    RD_A(1, 0, 0); RD_B(1, 0); stA(u + 2, 1);
    BAR(); LGKM(); MM16(0); BAR();
    // ph6: ktile u+1, kstep0, rows 64-127    | stage B(u+2, k1)
    RD_A(1, 0, 1); stB(u + 2, 1);
    BAR(); LGKM(); MM16(1); VM6(); BAR();
    // ph7: ktile u+1, kstep1, rows 0-63      | stage A(u+3, k0)
    RD_A(1, 1, 0); RD_B(1, 1); stA(u + 3, 0);
    BAR(); LGKM(); MM16(0); BAR();
    // ph8: ktile u+1, kstep1, rows 64-127    | stage B(u+3, k0)
    RD_A(1, 1, 1); stB(u + 3, 0);
    BAR(); LGKM(); MM16(1); VM6(); BAR();
  }
  asm volatile("s_waitcnt vmcnt(0)" ::: "memory");  // drain dangling prefetches
  BAR();   // all waves' dangling LDS writes landed before epilogue reuses S

  const int rbase = (lane >> 4) * 4;
  if (EPI == 1) {
    // QKV scatter: n0 block-constant -> sel (q/k/v), head h. d = n & 255.
    const int sel = n0 >> 10, h = (n0 >> 8) & 3;
    unsigned short* dst = (unsigned short*)out
        + (long)sel * ((long)B_ * H_ * T_ * HS_) + (long)h * T_ * HS_;
    #pragma unroll
    for (int j = 0; j < 4; ++j) {
      const int d = wc * 64 + j * 16 + fr;
      #pragma unroll
      for (int i = 0; i < 8; ++i) {
        #pragma unroll
        for (int r = 0; r < 4; ++r) {
          const int m = m0 + wr * 128 + i * 16 + rbase + r;
          const int bq = m >> 10, tq = m & 1023;
          dst[(long)bq * H_ * T_ * HS_ + (long)tq * HS_ + d] = f2bf(acc[i][j][r]);
        }
      }
    }
  } else {
    // LDS-transposed coalesced epilogue: each wave round-trips its 128x64
    // C-quadrant (two 128x32 halves) through its private 16 KB LDS region.
    // word-col XOR-banked by ((row&7)<<2): conflict-free write & read.
    float* lf = (float*)S;
    #pragma unroll
    for (int jh = 0; jh < 2; ++jh) {
      #pragma unroll
      for (int jj = 0; jj < 2; ++jj)
        #pragma unroll
        for (int i = 0; i < 8; ++i)
          #pragma unroll
          for (int r = 0; r < 4; ++r) {
            const int row = i * 16 + rbase + r;
            const int cw = (jj * 16 + fr) ^ ((row & 7) << 2);
            lf[wave * 4096 + row * 32 + cw] = acc[i][jh * 2 + jj][r];
          }
      // compiler inserts lgkm waits for the within-wave ds RAW dependence
      #pragma unroll
      for (int rs = 0; rs < 16; ++rs) {
        const int row = rs * 8 + (lane >> 3);
        const int c0 = (lane & 7) * 4;
        const int cw = c0 ^ ((row & 7) << 2);
        fx4 val = *reinterpret_cast<const fx4*>(&lf[wave * 4096 + row * 32 + cw]);
        const int n = n0 + wc * 64 + jh * 32 + c0;
        const int m = m0 + wr * 128 + row;
        const long off = outOff + ((long)(m >> 10)) * rowOuter + (long)(m & 1023) * ldc + n;
        if (BIAS) {
          const float4 bb = *reinterpret_cast<const float4*>(bias + n);
          val[0] += bb.x; val[1] += bb.y; val[2] += bb.z; val[3] += bb.w;
        }
        if (RELU) {
          val[0] = fmaxf(val[0], 0.f); val[1] = fmaxf(val[1], 0.f);
          val[2] = fmaxf(val[2], 0.f); val[3] = fmaxf(val[3], 0.f);
        }
        if (OUTBF) {
          usx4 o = { f2bf(val[0]), f2bf(val[1]), f2bf(val[2]), f2bf(val[3]) };
          *reinterpret_cast<usx4*>((unsigned short*)out + off) = o;
        } else {
          *reinterpret_cast<float4*>((float*)out + off) = *(const float4*)&val;
        }
      }
      __builtin_amdgcn_sched_barrier(0);  // keep jh=1 writes after jh=0 reads
    }
  }
}

// Tiled transpose + convert-to-bf16. src: (batch zb, R, Cc) TIN;
// dst base: dst + (zb>>zShiftT)*sOuter + (zb&mask)*(R*Cc); writes (Cc,R) bf16.
template<typename TIN>
__global__ __launch_bounds__(256) void transpose_k(const TIN* __restrict__ src,
    unsigned short* __restrict__ dst, int R, int Cc, int zShiftT, long sOuter) {
  __shared__ float ts[64][65];
  const long zb = blockIdx.z;
  src += zb * (long)R * Cc;
  dst += (zb >> zShiftT) * sOuter + (zb & ((1 << zShiftT) - 1)) * ((long)R * Cc);
  const int r0 = blockIdx.y * 64, c0 = blockIdx.x * 64;
  const int tr = threadIdx.x >> 4;
  const int tc = (threadIdx.x & 15) * 4;
  #pragma unroll
  for (int it = 0; it < 4; ++it) {
    const int r = tr + it * 16;
    float4 v;
    if constexpr (sizeof(TIN) == 4) {
      v = *reinterpret_cast<const float4*>(src + (long)(r0 + r) * Cc + c0 + tc);
    } else {
      usx4 u = *reinterpret_cast<const usx4*>(src + (long)(r0 + r) * Cc + c0 + tc);
      v.x = bf2f(u[0]); v.y = bf2f(u[1]); v.z = bf2f(u[2]); v.w = bf2f(u[3]);
    }
    ts[r][tc + 0] = v.x; ts[r][tc + 1] = v.y; ts[r][tc + 2] = v.z; ts[r][tc + 3] = v.w;
  }
  __syncthreads();
  #pragma unroll
  for (int it = 0; it < 4; ++it) {
    const int cj = tr + it * 16;
    usx4 o = { f2bf(ts[tc + 0][cj]), f2bf(ts[tc + 1][cj]),
               f2bf(ts[tc + 2][cj]), f2bf(ts[tc + 3][cj]) };
    *reinterpret_cast<usx4*>(dst + (long)(c0 + cj) * R + r0 + tc) = o;
  }
}

__global__ __launch_bounds__(256) void embed_k(const int* __restrict__ idx,
                                               const float* __restrict__ tok,
                                               const float* __restrict__ pos,
                                               float* __restrict__ x) {
  const int row = blockIdx.x;
  const int t = row & (T_ - 1);
  const int id = idx[row];
  const int c = threadIdx.x * 4;
  const float4 a = *reinterpret_cast<const float4*>(tok + (long)id * C_ + c);
  const float4 p = *reinterpret_cast<const float4*>(pos + (long)t * C_ + c);
  float4 ov = { a.x + p.x, a.y + p.y, a.z + p.z, a.w + p.w };
  *reinterpret_cast<float4*>(x + (long)row * C_ + c) = ov;
}

// LayerNorm: f32 in, bf16 out.
__global__ __launch_bounds__(256) void ln_k(const float* __restrict__ x,
                                            const float* __restrict__ g,
                                            const float* __restrict__ b,
                                            unsigned short* __restrict__ o) {
  __shared__ float red[8];
  const int row = blockIdx.x;
  const int c = threadIdx.x * 4;
  const float4 v = *reinterpret_cast<const float4*>(x + (long)row * C_ + c);
  float s1 = v.x + v.y + v.z + v.w;
  float s2 = v.x * v.x + v.y * v.y + v.z * v.z + v.w * v.w;
  #pragma unroll
  for (int off = 32; off; off >>= 1) {
    s1 += __shfl_xor(s1, off, 64);
    s2 += __shfl_xor(s2, off, 64);
  }
  const int lane = threadIdx.x & 63, w = threadIdx.x >> 6;
  if (lane == 0) { red[w] = s1; red[4 + w] = s2; }
  __syncthreads();
  s1 = red[0] + red[1] + red[2] + red[3];
  s2 = red[4] + red[5] + red[6] + red[7];
  const float mu = s1 * (1.f / C_);
  float var = s2 * (1.f / C_) - mu * mu;
  var = fmaxf(var, 0.f);
  const float inv = rsqrtf(var + 1e-5f);
  const float4 gg = *reinterpret_cast<const float4*>(g + c);
  const float4 bb = *reinterpret_cast<const float4*>(b + c);
  usx4 ov;
  ov[0] = f2bf((v.x - mu) * inv * gg.x + bb.x);
  ov[1] = f2bf((v.y - mu) * inv * gg.y + bb.y);
  ov[2] = f2bf((v.z - mu) * inv * gg.z + bb.z);
  ov[3] = f2bf((v.w - mu) * inv * gg.w + bb.w);
  *reinterpret_cast<usx4*>(o + (long)row * C_ + c) = ov;
}

// Row softmax on S^T[s][t] (bf16), masked to t>=s, scale 1/32; bf16 alphaT out.
__global__ __launch_bounds__(256) void colsm_k(const unsigned short* __restrict__ a,
                                               unsigned short* __restrict__ aT) {
  __shared__ float red[8];
  const int row = blockIdx.x;
  const int s = row & (T_ - 1);
  const unsigned short* p = a + (long)row * T_;
  const int t0 = threadIdx.x * 4;
  const usx4 u = *reinterpret_cast<const usx4*>(p + t0);
  const float scale = 0.03125f;  // 1/sqrt(C)=1/32
  float vals[4];
  float m = -1e30f;
  #pragma unroll
  for (int j = 0; j < 4; ++j) {
    vals[j] = (t0 + j >= s) ? bf2f(u[j]) * scale : -1e30f;
    m = fmaxf(m, vals[j]);
  }
  #pragma unroll
  for (int off = 32; off; off >>= 1) m = fmaxf(m, __shfl_xor(m, off, 64));
  const int lane = threadIdx.x & 63, w = threadIdx.x >> 6;
  if (lane == 0) red[w] = m;
  __syncthreads();
  m = fmaxf(fmaxf(red[0], red[1]), fmaxf(red[2], red[3]));
  __syncthreads();
  float e[4], sum = 0.f;
  #pragma unroll
  for (int j = 0; j < 4; ++j) {
    e[j] = (t0 + j >= s) ? __expf(vals[j] - m) : 0.f;
    sum += e[j];
  }
  #pragma unroll
  for (int off = 32; off; off >>= 1) sum += __shfl_xor(sum, off, 64);
  if (lane == 0) red[w] = sum;
  __syncthreads();
  sum = red[0] + red[1] + red[2] + red[3];
  const float inv = 1.f / sum;
  usx4 ov = { f2bf(e[0] * inv), f2bf(e[1] * inv), f2bf(e[2] * inv), f2bf(e[3] * inv) };
  *reinterpret_cast<usx4*>(aT + (long)row * T_ + t0) = ov;
}

extern "C" void kernel_launch(void* const* d_in, const int* in_sizes, int n_in,
                              void* d_out, int out_size, void* d_ws, size_t ws_size,
                              hipStream_t stream) {
  const int*   idx    = (const int*)d_in[0];
  const float* tok    = (const float*)d_in[1];
  const float* pos    = (const float*)d_in[2];
  const float* wq     = (const float*)d_in[3];
  const float* wk     = (const float*)d_in[4];
  const float* wv     = (const float*)d_in[5];
  const float* proj_w = (const float*)d_in[6];
  const float* proj_b = (const float*)d_in[7];
  const float* ln1_g  = (const float*)d_in[8];
  const float* ln1_b  = (const float*)d_in[9];
  const float* ln2_g  = (const float*)d_in[10];
  const float* ln2_b  = (const float*)d_in[11];
  const float* ff_w1  = (const float*)d_in[12];
  const float* ff_b1  = (const float*)d_in[13];
  const float* ff_w2  = (const float*)d_in[14];
  const float* ff_b2  = (const float*)d_in[15];
  const float* lnf_g  = (const float*)d_in[16];
  const float* lnf_b  = (const float*)d_in[17];
  const float* head_w = (const float*)d_in[18];
  const float* head_b = (const float*)d_in[19];
  float* outp = (float*)d_out;

  typedef unsigned short us;
  char* w = (char*)d_ws;
  float* x    = (float*)(w + 0);            // 16 MB (M,C) f32
  us* xn      = (us*)(w + 16777216);        //  8 MB (M,C)
  us* qkv     = (us*)(w + 25165824);        // 24 MB: q,k,v each (B,H,T,HS)
  us* kptr    = qkv + 4194304;
  us* vptr    = qkv + 8388608;
  us* vT      = (us*)(w + 50331648);        //  8 MB (B,H,HS,T)
  us* yc      = (us*)(w + 58720256);        //  8 MB (B,T,C)
  us* sc      = (us*)(w + 67108864);        // 32 MB (B*H,T,T) scores S^T
  us* headT   = (us*)(w + 67108864);        // 65.5 MB alias over sc+alpha
  us* alpha   = (us*)(w + 100663296);       // 32 MB (B*H,T,T)
  us* aT      = (us*)(w + 134217728);       // 32 MB (B*H,T,T)
  us* hidden  = aT;                         // alias (aT dead after transpose)
  us* wqkvT   = (us*)(w + 167772160);       // 24 MB (L,3,H,HS,C)
  us* projT   = (us*)(w + 192937984);       //  8 MB (L,C,C)
  us* ff1T    = (us*)(w + 201326592);       // 32 MB (L,4C,C)
  us* ff2T    = (us*)(w + 234881024);       // 32 MB (L,C,4C)
  if (ws_size < (size_t)268435456) return;  // fail loudly

  const long HHC = (long)H_ * HS_ * C_;     // per-matrix per-layer us
  // ---- one-time weight transpose + bf16 convert ----
  transpose_k<float><<<dim3(HS_/64, C_/64, L_*H_), 256, 0, stream>>>(wq, wqkvT,           C_, HS_, 2, 3*HHC);
  transpose_k<float><<<dim3(HS_/64, C_/64, L_*H_), 256, 0, stream>>>(wk, wqkvT + HHC,     C_, HS_, 2, 3*HHC);
  transpose_k<float><<<dim3(HS_/64, C_/64, L_*H_), 256, 0, stream>>>(wv, wqkvT + 2*HHC,   C_, HS_, 2, 3*HHC);
  transpose_k<float><<<dim3(C_/64, C_/64, L_), 256, 0, stream>>>(proj_w, projT, C_, C_, 0, (long)C_*C_);
  transpose_k<float><<<dim3(4*C_/64, C_/64, L_), 256, 0, stream>>>(ff_w1, ff1T, C_, 4*C_, 0, (long)C_*4*C_);
  transpose_k<float><<<dim3(C_/64, 4*C_/64, L_), 256, 0, stream>>>(ff_w2, ff2T, 4*C_, C_, 0, (long)4*C_*C_);

  embed_k<<<M_, 256, 0, stream>>>(idx, tok, pos, x);

  for (int l = 0; l < L_; ++l) {
    ln_k<<<M_, 256, 0, stream>>>(x, ln1_g + l * C_, ln1_b + l * C_, xn);

    // merged QKV: N=3072 (sel,h,d) scatter epilogue -> qkv (3,B,H,T,HS)
    dim3 gqkv(M_/256, 3*C_/256, 1);
    gemm256<0,0,1,1><<<gqkv, 512, 0, stream>>>(xn, wqkvT + l * 3 * HHC, nullptr, qkv,
        C_, C_, C_, 0, 0, 0, 0, 0);

    // S^T[s][t] = sum_d K[s,d]*Q[t,d]  -> bf16 (scale applied in colsm)
    dim3 gs(T_/256, T_/256, B_*H_);
    gemm256<0,0,1,0><<<gs, 512, 0, stream>>>(kptr, qkv, nullptr, sc,
        HS_, HS_, HS_, T_, (long)T_*HS_, (long)T_*HS_, (long)T_*T_, 0);

    // softmax over t (query axis) per (b,h,s) row -> bf16 alphaT
    colsm_k<<<B_*H_*T_, 256, 0, stream>>>(sc, aT);

    // alphaT (s,t) -> alpha (t,s); v (t,d) -> vT (d,t)
    transpose_k<us><<<dim3(T_/64, T_/64, B_*H_), 256, 0, stream>>>(aT, alpha, T_, T_, 0, (long)T_*T_);
    transpose_k<us><<<dim3(HS_/64, T_/64, B_*H_), 256, 0, stream>>>(vptr, vT, T_, HS_, 0, (long)T_*HS_);

    // y[t,d] = sum_s alpha[t,s]*vT[d,s] -> yc (B,T,C) at col h*HS, bf16
    dim3 gp(T_/128, HS_/128, B_*H_);
    gemm_bf16<0,0,0,1><<<gp, 256, 0, stream>>>(alpha, vT, nullptr, nullptr, yc,
        T_, HS_, T_, T_, T_, C_, (long)T_*T_, (long)HS_*T_, (long)T_*C_, HS_, 2, (long)T_*C_);

    // x = x + yc @ proj_w + proj_b   (f32 out)
    dim3 gj(M_/128, C_/128, 1);
    gemm_bf16<1,1,0,0><<<gj, 256, 0, stream>>>(yc, projT + (long)l*C_*C_, proj_b + l*C_, x, x,
        M_, C_, C_, C_, C_, C_, 0, 0, 0, 0, 0, (long)T_*C_);

    ln_k<<<M_, 256, 0, stream>>>(x, ln2_g + l * C_, ln2_b + l * C_, xn);

    // hidden = relu(xn @ ff_w1 + b1)  bf16
    dim3 g1(M_/256, 4*C_/256, 1);
    gemm256<1,1,1,0><<<g1, 512, 0, stream>>>(xn, ff1T + (long)l*4*C_*C_, ff_b1 + (long)l*4*C_,
        hidden, C_, C_, C_, 4*C_, 0, 0, 0, (long)1024*4*C_);

    // x = x + hidden @ ff_w2 + b2   (f32 out)
    dim3 g2(M_/128, C_/128, 1);
    gemm_bf16<1,1,0,0><<<g2, 256, 0, stream>>>(hidden, ff2T + (long)l*C_*4*C_, ff_b2 + l*C_, x, x,
        M_, C_, 4*C_, 4*C_, 4*C_, C_, 0, 0, 0, 0, 0, (long)T_*C_);
  }

  ln_k<<<M_, 256, 0, stream>>>(x, lnf_g, lnf_b, xn);

  // head weight transpose into the (now dead) scores/alpha region
  transpose_k<float><<<dim3(V_/64, C_/64, 1), 256, 0, stream>>>(head_w, headT, C_, V_, 0, (long)C_*V_);

  dim3 gh(M_/256, V_/256, 1);
  gemm256<1,0,0,0><<<gh, 512, 0, stream>>>(xn, headT, head_b, outp,
      C_, C_, C_, V_, 0, 0, 0, (long)1024*V_);
}

// Round 7
// 1605.059 us; speedup vs baseline: 3.7862x; 1.0028x over previous
//
#include <hip/hip_runtime.h>

// GPT forward: L=4, H=4, C=1024, HS=256, V=32000, B=4, T=1024. f32 in/out.
// bf16 MFMA 16x16x32. Big GEMMs (head, FF1, QKV-merged, scores): 256x256-tile
// 8-wave pipelined kernel: read-ahead register double-buffering (LDS reads of
// region q+1 overlap MFMA pipe of region q), 1 barrier/region, counted
// vmcnt(8), st_16x32 swizzle, setprio, LDS-transposed coalesced epilogue.
// Rest: 128x128 m97-structure kernel.

#define C_  1024
#define T_  1024
#define HS_ 256
#define H_  4
#define L_  4
#define V_  32000
#define B_  4
#define M_  4096   // B_*T_

typedef __attribute__((ext_vector_type(8))) short  bfx8;
typedef __attribute__((ext_vector_type(4))) float  fx4;
typedef __attribute__((ext_vector_type(4))) unsigned short usx4;

__device__ __forceinline__ unsigned short f2bf(float f) {
  unsigned int u = __builtin_bit_cast(unsigned int, f);
  u += 0x7fffu + ((u >> 16) & 1u);          // round-to-nearest-even
  return (unsigned short)(u >> 16);
}
__device__ __forceinline__ float bf2f(unsigned short u) {
  return __builtin_bit_cast(float, ((unsigned int)u) << 16);
}

// async global->LDS, 16 B per lane. LDS dest = (wave-uniform base) + lane*16.
__device__ __forceinline__ void gload16(const unsigned short* g, unsigned short* l) {
  __builtin_amdgcn_global_load_lds(
      (const __attribute__((address_space(1))) unsigned int*)g,
      (__attribute__((address_space(3))) unsigned int*)l, 16, 0, 0);
}

// ============================ 128x128 kernel =================================
template<int BIAS, int RES, int RELU, int OUTBF>
__global__ __launch_bounds__(256, 2) void gemm_bf16(
    const unsigned short* __restrict__ A, const unsigned short* __restrict__ Bm,
    const float* __restrict__ bias, const float* __restrict__ res,
    void* __restrict__ out,
    int M, int N, int K, int lda, int ldb, int ldc,
    long sA, long sB, long sC1, long sC2, int zShift, long rowOuter)
{
  __shared__ unsigned short As[128 * 32];
  __shared__ unsigned short Bs[128 * 32];
  const int z = blockIdx.z;
  A  += (long)z * sA;
  Bm += (long)z * sB;
  const long outOff = ((long)(z >> zShift)) * sC1 + (long)(z & ((1 << zShift) - 1)) * sC2;
  const int m0 = blockIdx.x * 128, n0 = blockIdx.y * 128;
  const int tid = threadIdx.x;
  const int lane = tid & 63, wave = tid >> 6;
  const int wm = (wave >> 1) * 64, wn = (wave & 1) * 64;
  const int fr = lane & 15, kb = lane >> 4;
  const int sr = lane >> 2;
  const int csw = (((lane & 3) ^ ((lane >> 3) & 3)) << 3);
  const int aco = ((kb ^ ((lane >> 1) & 3)) << 3);

  fx4 acc[4][4] = {};

  for (int k0 = 0; k0 < K; k0 += 32) {
    #pragma unroll
    for (int i = 0; i < 2; ++i) {
      const int c = wave * 2 + i;
      gload16(A  + (long)(m0 + c * 16 + sr) * lda + k0 + csw, &As[c * 512]);
      gload16(Bm + (long)(n0 + c * 16 + sr) * ldb + k0 + csw, &Bs[c * 512]);
    }
    __syncthreads();
    bfx8 af[4], bf[4];
    #pragma unroll
    for (int i = 0; i < 4; ++i)
      af[i] = *reinterpret_cast<const bfx8*>(&As[(wm + i * 16 + fr) * 32 + aco]);
    #pragma unroll
    for (int j = 0; j < 4; ++j)
      bf[j] = *reinterpret_cast<const bfx8*>(&Bs[(wn + j * 16 + fr) * 32 + aco]);
    #pragma unroll
    for (int i = 0; i < 4; ++i)
      #pragma unroll
      for (int j = 0; j < 4; ++j)
        acc[i][j] = __builtin_amdgcn_mfma_f32_16x16x32_bf16(af[i], bf[j], acc[i][j], 0, 0, 0);
    __syncthreads();
  }

  const float* resp = res;
  if (RES) resp += outOff;
  const int rbase = (lane >> 4) * 4;
  #pragma unroll
  for (int j = 0; j < 4; ++j) {
    const int n = n0 + wn + j * 16 + fr;
    float bv = 0.f;
    if (BIAS) bv = bias[n];
    #pragma unroll
    for (int i = 0; i < 4; ++i) {
      #pragma unroll
      for (int r = 0; r < 4; ++r) {
        const int m = m0 + wm + i * 16 + rbase + r;
        const long off = outOff + ((long)(m >> 10)) * rowOuter + (long)(m & 1023) * ldc + n;
        float val = acc[i][j][r] + bv;
        if (RELU) val = fmaxf(val, 0.f);
        if (RES) val += resp[((long)(m >> 10)) * rowOuter + (long)(m & 1023) * ldc + n];
        if (OUTBF) ((unsigned short*)out)[off] = f2bf(val);
        else       ((float*)out)[off] = val;
      }
    }
  }
}

// ============================ 256x256 pipelined kernel =======================
// 512 thr = 8 waves (2M x 4N), wave tile 128x64, BK=64 (2 ksteps of 32).
// LDS: 8 slots [256 rows][32 K] bf16: A(par,kh) @ (par*2+kh)*8192, B @ +32768.
// Region q: {stage 1 half-tile; ds_reads for region q+1 (alt reg set);
// 16 MFMA on current set; lgkmcnt(0)+schedbar; [even q] vmcnt(8); s_barrier}.
// MFMA operands were lgkm-waited in the PREVIOUS region -> LDS reads overlap
// the MFMA pipe. Slot lifetimes & vmcnt coverage verified for all pairs.
#define BAR() __builtin_amdgcn_s_barrier()
#define LGKM() { asm volatile("s_waitcnt lgkmcnt(0)" ::: "memory"); \
                 __builtin_amdgcn_sched_barrier(0); }
#define VM8()  asm volatile("s_waitcnt vmcnt(8)" ::: "memory")
#define STA(tau, kh) { const int tc = (tau) < NT ? (tau) : NT - 1; \
  const unsigned short* src = A + (long)(m0 + wave * 16 + srow) * lda + tc * 64 + (kh) * 32 + csw; \
  unsigned short* d = &S[(((tau) & 1) * 2 + (kh)) * 8192 + wave * 512]; \
  gload16(src, d); gload16(src + (long)128 * lda, d + 4096); }
#define STB(tau, kh) { const int tc = (tau) < NT ? (tau) : NT - 1; \
  const unsigned short* src = Bm + (long)(n0 + wave * 16 + srow) * ldb + tc * 64 + (kh) * 32 + csw; \
  unsigned short* d = &S[32768 + (((tau) & 1) * 2 + (kh)) * 8192 + wave * 512]; \
  gload16(src, d); gload16(src + (long)128 * ldb, d + 4096); }
#define RDA(dst, par, kh, rh) { _Pragma("unroll") for (int i = 0; i < 4; ++i) \
  dst[i] = *reinterpret_cast<const bfx8*>(&S[((par)*2+(kh))*8192 + (wr*128 + (rh)*64 + i*16 + fr)*32 + aco]); }
#define RDB(dst, par, kh) { _Pragma("unroll") for (int j = 0; j < 4; ++j) \
  dst[j] = *reinterpret_cast<const bfx8*>(&S[32768 + ((par)*2+(kh))*8192 + (wc*64 + j*16 + fr)*32 + aco]); }
#define MM(rh, afx, bfx) { __builtin_amdgcn_s_setprio(1); \
  _Pragma("unroll") for (int i = 0; i < 4; ++i) { _Pragma("unroll") for (int j = 0; j < 4; ++j) \
    acc[(rh)*4+i][j] = __builtin_amdgcn_mfma_f32_16x16x32_bf16(afx[i], bfx[j], acc[(rh)*4+i][j], 0, 0, 0); } \
  __builtin_amdgcn_s_setprio(0); }

template<int BIAS, int RELU, int OUTBF, int EPI>
__global__ __launch_bounds__(512, 2) void gemm256(
    const unsigned short* __restrict__ A, const unsigned short* __restrict__ Bm,
    const float* __restrict__ bias, void* __restrict__ out,
    int K, int lda, int ldb, int ldc,
    long sA, long sB, long sC1, long rowOuter)
{
  __shared__ unsigned short S[65536];   // 128 KB
  const int z = blockIdx.z;
  A  += (long)z * sA;
  Bm += (long)z * sB;
  const long outOff = (long)z * sC1;
  const int m0 = blockIdx.x * 256, n0 = blockIdx.y * 256;
  const int tid = threadIdx.x;
  const int lane = tid & 63, wave = tid >> 6;
  const int wr = wave >> 2, wc = wave & 3;
  const int fr = lane & 15, kb = lane >> 4;
  const int srow = lane >> 2;
  // st_16x32: 16B slot-in-row ^= ((row&15)>>3)<<1. Pre-swizzled global source.
  const int csw = (((lane & 3) ^ (((lane >> 5) & 1) << 1)) << 3);
  const int aco = ((kb ^ (((fr >> 3) & 1) << 1)) << 3);
  const int NT = K >> 6;    // K-tiles of 64 (NT even for all our shapes)
  const int NI = NT >> 1;

  fx4 acc[8][4] = {};
  bfx8 afa[4], afb[4], bf0[4], bf1[4];

  // prologue: stage ktiles 0,1 fully (8 half-tiles, consumption order)
  STB(0, 0); STA(0, 0); STB(0, 1); STA(0, 1);
  STB(1, 0); STA(1, 0); STB(1, 1); STA(1, 1);
  VM8();                      // oldest 8 done: (0,0)+(0,1) A&B landed
  BAR();
  RDA(afa, 0, 0, 0); RDB(bf1, 0, 0);   // regs for region r1's MFMA
  LGKM();
  BAR();

  for (int t = 0; t < NI; ++t) {
    const int u = 2 * t;
    // r1: MFMA (u,k0,rh0)
    STB(u + 2, 0); RDA(afb, 0, 0, 1);                 MM(0, afa, bf1); LGKM(); BAR();
    // r2: MFMA (u,k0,rh1)
    STA(u + 2, 0); RDA(afa, 0, 1, 0); RDB(bf0, 0, 1); MM(1, afb, bf1); LGKM(); VM8(); BAR();
    // r3: MFMA (u,k1,rh0)
    STB(u + 2, 1); RDA(afb, 0, 1, 1);                 MM(0, afa, bf0); LGKM(); BAR();
    // r4: MFMA (u,k1,rh1)
    STA(u + 2, 1); RDA(afa, 1, 0, 0); RDB(bf1, 1, 0); MM(1, afb, bf0); LGKM(); VM8(); BAR();
    // r5: MFMA (u+1,k0,rh0)
    STB(u + 3, 0); RDA(afb, 1, 0, 1);                 MM(0, afa, bf1); LGKM(); BAR();
    // r6: MFMA (u+1,k0,rh1)
    STA(u + 3, 0); RDA(afa, 1, 1, 0); RDB(bf0, 1, 1); MM(1, afb, bf1); LGKM(); VM8(); BAR();
    // r7: MFMA (u+1,k1,rh0)
    STB(u + 3, 1); RDA(afb, 1, 1, 1);                 MM(0, afa, bf0); LGKM(); BAR();
    // r8: MFMA (u+1,k1,rh1)
    STA(u + 3, 1); RDA(afa, 0, 0, 0); RDB(bf1, 0, 0); MM(1, afb, bf0); LGKM(); VM8(); BAR();
  }
  asm volatile("s_waitcnt vmcnt(0)" ::: "memory");  // drain dangling prefetches
  BAR();   // no in-flight gload may write S while epilogue reuses it

  const int rbase = (lane >> 4) * 4;
  if (EPI == 1) {
    // QKV scatter: n0 block-constant -> sel (q/k/v), head h. d = n & 255.
    const int sel = n0 >> 10, h = (n0 >> 8) & 3;
    unsigned short* dst = (unsigned short*)out
        + (long)sel * ((long)B_ * H_ * T_ * HS_) + (long)h * T_ * HS_;
    #pragma unroll
    for (int j = 0; j < 4; ++j) {
      const int d = wc * 64 + j * 16 + fr;
      #pragma unroll
      for (int i = 0; i < 8; ++i) {
        #pragma unroll
        for (int r = 0; r < 4; ++r) {
          const int m = m0 + wr * 128 + i * 16 + rbase + r;
          const int bq = m >> 10, tq = m & 1023;
          dst[(long)bq * H_ * T_ * HS_ + (long)tq * HS_ + d] = f2bf(acc[i][j][r]);
        }
      }
    }
  } else {
    // LDS-transposed coalesced epilogue: wave round-trips its 128x64 quadrant
    // through its private 16 KB region; word-col XOR by ((row&7)<<2).
    float* lf = (float*)S;
    #pragma unroll
    for (int jh = 0; jh < 2; ++jh) {
      #pragma unroll
      for (int jj = 0; jj < 2; ++jj)
        #pragma unroll
        for (int i = 0; i < 8; ++i)
          #pragma unroll
          for (int r = 0; r < 4; ++r) {
            const int row = i * 16 + rbase + r;
            const int cw = (jj * 16 + fr) ^ ((row & 7) << 2);
            lf[wave * 4096 + row * 32 + cw] = acc[i][jh * 2 + jj][r];
          }
      #pragma unroll
      for (int rs = 0; rs < 16; ++rs) {
        const int row = rs * 8 + (lane >> 3);
        const int c0 = (lane & 7) * 4;
        const int cw = c0 ^ ((row & 7) << 2);
        fx4 val = *reinterpret_cast<const fx4*>(&lf[wave * 4096 + row * 32 + cw]);
        const int n = n0 + wc * 64 + jh * 32 + c0;
        const int m = m0 + wr * 128 + row;
        const long off = outOff + ((long)(m >> 10)) * rowOuter + (long)(m & 1023) * ldc + n;
        if (BIAS) {
          const float4 bb = *reinterpret_cast<const float4*>(bias + n);
          val[0] += bb.x; val[1] += bb.y; val[2] += bb.z; val[3] += bb.w;
        }
        if (RELU) {
          val[0] = fmaxf(val[0], 0.f); val[1] = fmaxf(val[1], 0.f);
          val[2] = fmaxf(val[2], 0.f); val[3] = fmaxf(val[3], 0.f);
        }
        if (OUTBF) {
          usx4 o = { f2bf(val[0]), f2bf(val[1]), f2bf(val[2]), f2bf(val[3]) };
          *reinterpret_cast<usx4*>((unsigned short*)out + off) = o;
        } else {
          *reinterpret_cast<float4*>((float*)out + off) = *(const float4*)&val;
        }
      }
      __builtin_amdgcn_sched_barrier(0);  // keep jh=1 writes after jh=0 reads
    }
  }
}

// Tiled transpose + convert-to-bf16. src: (batch zb, R, Cc) TIN;
// dst base: dst + (zb>>zShiftT)*sOuter + (zb&mask)*(R*Cc); writes (Cc,R) bf16.
template<typename TIN>
__global__ __launch_bounds__(256) void transpose_k(const TIN* __restrict__ src,
    unsigned short* __restrict__ dst, int R, int Cc, int zShiftT, long sOuter) {
  __shared__ float ts[64][65];
  const long zb = blockIdx.z;
  src += zb * (long)R * Cc;
  dst += (zb >> zShiftT) * sOuter + (zb & ((1 << zShiftT) - 1)) * ((long)R * Cc);
  const int r0 = blockIdx.y * 64, c0 = blockIdx.x * 64;
  const int tr = threadIdx.x >> 4;
  const int tc = (threadIdx.x & 15) * 4;
  #pragma unroll
  for (int it = 0; it < 4; ++it) {
    const int r = tr + it * 16;
    float4 v;
    if constexpr (sizeof(TIN) == 4) {
      v = *reinterpret_cast<const float4*>(src + (long)(r0 + r) * Cc + c0 + tc);
    } else {
      usx4 u = *reinterpret_cast<const usx4*>(src + (long)(r0 + r) * Cc + c0 + tc);
      v.x = bf2f(u[0]); v.y = bf2f(u[1]); v.z = bf2f(u[2]); v.w = bf2f(u[3]);
    }
    ts[r][tc + 0] = v.x; ts[r][tc + 1] = v.y; ts[r][tc + 2] = v.z; ts[r][tc + 3] = v.w;
  }
  __syncthreads();
  #pragma unroll
  for (int it = 0; it < 4; ++it) {
    const int cj = tr + it * 16;
    usx4 o = { f2bf(ts[tc + 0][cj]), f2bf(ts[tc + 1][cj]),
               f2bf(ts[tc + 2][cj]), f2bf(ts[tc + 3][cj]) };
    *reinterpret_cast<usx4*>(dst + (long)(c0 + cj) * R + r0 + tc) = o;
  }
}

__global__ __launch_bounds__(256) void embed_k(const int* __restrict__ idx,
                                               const float* __restrict__ tok,
                                               const float* __restrict__ pos,
                                               float* __restrict__ x) {
  const int row = blockIdx.x;
  const int t = row & (T_ - 1);
  const int id = idx[row];
  const int c = threadIdx.x * 4;
  const float4 a = *reinterpret_cast<const float4*>(tok + (long)id * C_ + c);
  const float4 p = *reinterpret_cast<const float4*>(pos + (long)t * C_ + c);
  float4 ov = { a.x + p.x, a.y + p.y, a.z + p.z, a.w + p.w };
  *reinterpret_cast<float4*>(x + (long)row * C_ + c) = ov;
}

// LayerNorm: f32 in, bf16 out.
__global__ __launch_bounds__(256) void ln_k(const float* __restrict__ x,
                                            const float* __restrict__ g,
                                            const float* __restrict__ b,
                                            unsigned short* __restrict__ o) {
  __shared__ float red[8];
  const int row = blockIdx.x;
  const int c = threadIdx.x * 4;
  const float4 v = *reinterpret_cast<const float4*>(x + (long)row * C_ + c);
  float s1 = v.x + v.y + v.z + v.w;
  float s2 = v.x * v.x + v.y * v.y + v.z * v.z + v.w * v.w;
  #pragma unroll
  for (int off = 32; off; off >>= 1) {
    s1 += __shfl_xor(s1, off, 64);
    s2 += __shfl_xor(s2, off, 64);
  }
  const int lane = threadIdx.x & 63, w = threadIdx.x >> 6;
  if (lane == 0) { red[w] = s1; red[4 + w] = s2; }
  __syncthreads();
  s1 = red[0] + red[1] + red[2] + red[3];
  s2 = red[4] + red[5] + red[6] + red[7];
  const float mu = s1 * (1.f / C_);
  float var = s2 * (1.f / C_) - mu * mu;
  var = fmaxf(var, 0.f);
  const float inv = rsqrtf(var + 1e-5f);
  const float4 gg = *reinterpret_cast<const float4*>(g + c);
  const float4 bb = *reinterpret_cast<const float4*>(b + c);
  usx4 ov;
  ov[0] = f2bf((v.x - mu) * inv * gg.x + bb.x);
  ov[1] = f2bf((v.y - mu) * inv * gg.y + bb.y);
  ov[2] = f2bf((v.z - mu) * inv * gg.z + bb.z);
  ov[3] = f2bf((v.w - mu) * inv * gg.w + bb.w);
  *reinterpret_cast<usx4*>(o + (long)row * C_ + c) = ov;
}

// Row softmax on S^T[s][t] (bf16), masked to t>=s, scale 1/32; bf16 alphaT out.
__global__ __launch_bounds__(256) void colsm_k(const unsigned short* __restrict__ a,
                                               unsigned short* __restrict__ aT) {
  __shared__ float red[8];
  const int row = blockIdx.x;
  const int s = row & (T_ - 1);
  const unsigned short* p = a + (long)row * T_;
  const int t0 = threadIdx.x * 4;
  const usx4 u = *reinterpret_cast<const usx4*>(p + t0);
  const float scale = 0.03125f;  // 1/sqrt(C)=1/32
  float vals[4];
  float m = -1e30f;
  #pragma unroll
  for (int j = 0; j < 4; ++j) {
    vals[j] = (t0 + j >= s) ? bf2f(u[j]) * scale : -1e30f;
    m = fmaxf(m, vals[j]);
  }
  #pragma unroll
  for (int off = 32; off; off >>= 1) m = fmaxf(m, __shfl_xor(m, off, 64));
  const int lane = threadIdx.x & 63, w = threadIdx.x >> 6;
  if (lane == 0) red[w] = m;
  __syncthreads();
  m = fmaxf(fmaxf(red[0], red[1]), fmaxf(red[2], red[3]));
  __syncthreads();
  float e[4], sum = 0.f;
  #pragma unroll
  for (int j = 0; j < 4; ++j) {
    e[j] = (t0 + j >= s) ? __expf(vals[j] - m) : 0.f;
    sum += e[j];
  }
  #pragma unroll
  for (int off = 32; off; off >>= 1) sum += __shfl_xor(sum, off, 64);
  if (lane == 0) red[w] = sum;
  __syncthreads();
  sum = red[0] + red[1] + red[2] + red[3];
  const float inv = 1.f / sum;
  usx4 ov = { f2bf(e[0] * inv), f2bf(e[1] * inv), f2bf(e[2] * inv), f2bf(e[3] * inv) };
  *reinterpret_cast<usx4*>(aT + (long)row * T_ + t0) = ov;
}

extern "C" void kernel_launch(void* const* d_in, const int* in_sizes, int n_in,
                              void* d_out, int out_size, void* d_ws, size_t ws_size,
                              hipStream_t stream) {
  const int*   idx    = (const int*)d_in[0];
  const float* tok    = (const float*)d_in[1];
  const float* pos    = (const float*)d_in[2];
  const float* wq     = (const float*)d_in[3];
  const float* wk     = (const float*)d_in[4];
  const float* wv     = (const float*)d_in[5];
  const float* proj_w = (const float*)d_in[6];
  const float* proj_b = (const float*)d_in[7];
  const float* ln1_g  = (const float*)d_in[8];
  const float* ln1_b  = (const float*)d_in[9];
  const float* ln2_g  = (const float*)d_in[10];
  const float* ln2_b  = (const float*)d_in[11];
  const float* ff_w1  = (const float*)d_in[12];
  const float* ff_b1  = (const float*)d_in[13];
  const float* ff_w2  = (const float*)d_in[14];
  const float* ff_b2  = (const float*)d_in[15];
  const float* lnf_g  = (const float*)d_in[16];
  const float* lnf_b  = (const float*)d_in[17];
  const float* head_w = (const float*)d_in[18];
  const float* head_b = (const float*)d_in[19];
  float* outp = (float*)d_out;

  typedef unsigned short us;
  char* w = (char*)d_ws;
  float* x    = (float*)(w + 0);            // 16 MB (M,C) f32
  us* xn      = (us*)(w + 16777216);        //  8 MB (M,C)
  us* qkv     = (us*)(w + 25165824);        // 24 MB: q,k,v each (B,H,T,HS)
  us* kptr    = qkv + 4194304;
  us* vptr    = qkv + 8388608;
  us* vT      = (us*)(w + 50331648);        //  8 MB (B,H,HS,T)
  us* yc      = (us*)(w + 58720256);        //  8 MB (B,T,C)
  us* sc      = (us*)(w + 67108864);        // 32 MB (B*H,T,T) scores S^T
  us* headT   = (us*)(w + 67108864);        // 65.5 MB alias over sc+alpha
  us* alpha   = (us*)(w + 100663296);       // 32 MB (B*H,T,T)
  us* aT      = (us*)(w + 134217728);       // 32 MB (B*H,T,T)
  us* hidden  = aT;                         // alias (aT dead after transpose)
  us* wqkvT   = (us*)(w + 167772160);       // 24 MB (L,3,H,HS,C)
  us* projT   = (us*)(w + 192937984);       //  8 MB (L,C,C)
  us* ff1T    = (us*)(w + 201326592);       // 32 MB (L,4C,C)
  us* ff2T    = (us*)(w + 234881024);       // 32 MB (L,C,4C)
  if (ws_size < (size_t)268435456) return;  // fail loudly

  const long HHC = (long)H_ * HS_ * C_;     // per-matrix per-layer us
  // ---- one-time weight transpose + bf16 convert ----
  transpose_k<float><<<dim3(HS_/64, C_/64, L_*H_), 256, 0, stream>>>(wq, wqkvT,           C_, HS_, 2, 3*HHC);
  transpose_k<float><<<dim3(HS_/64, C_/64, L_*H_), 256, 0, stream>>>(wk, wqkvT + HHC,     C_, HS_, 2, 3*HHC);
  transpose_k<float><<<dim3(HS_/64, C_/64, L_*H_), 256, 0, stream>>>(wv, wqkvT + 2*HHC,   C_, HS_, 2, 3*HHC);
  transpose_k<float><<<dim3(C_/64, C_/64, L_), 256, 0, stream>>>(proj_w, projT, C_, C_, 0, (long)C_*C_);
  transpose_k<float><<<dim3(4*C_/64, C_/64, L_), 256, 0, stream>>>(ff_w1, ff1T, C_, 4*C_, 0, (long)C_*4*C_);
  transpose_k<float><<<dim3(C_/64, 4*C_/64, L_), 256, 0, stream>>>(ff_w2, ff2T, 4*C_, C_, 0, (long)4*C_*C_);

  embed_k<<<M_, 256, 0, stream>>>(idx, tok, pos, x);

  for (int l = 0; l < L_; ++l) {
    ln_k<<<M_, 256, 0, stream>>>(x, ln1_g + l * C_, ln1_b + l * C_, xn);

    // merged QKV: N=3072 (sel,h,d) scatter epilogue -> qkv (3,B,H,T,HS)
    dim3 gqkv(M_/256, 3*C_/256, 1);
    gemm256<0,0,1,1><<<gqkv, 512, 0, stream>>>(xn, wqkvT + l * 3 * HHC, nullptr, qkv,
        C_, C_, C_, 0, 0, 0, 0, 0);

    // S^T[s][t] = sum_d K[s,d]*Q[t,d]  -> bf16 (scale applied in colsm)
    dim3 gs(T_/256, T_/256, B_*H_);
    gemm256<0,0,1,0><<<gs, 512, 0, stream>>>(kptr, qkv, nullptr, sc,
        HS_, HS_, HS_, T_, (long)T_*HS_, (long)T_*HS_, (long)T_*T_, 0);

    // softmax over t (query axis) per (b,h,s) row -> bf16 alphaT
    colsm_k<<<B_*H_*T_, 256, 0, stream>>>(sc, aT);

    // alphaT (s,t) -> alpha (t,s); v (t,d) -> vT (d,t)
    transpose_k<us><<<dim3(T_/64, T_/64, B_*H_), 256, 0, stream>>>(aT, alpha, T_, T_, 0, (long)T_*T_);
    transpose_k<us><<<dim3(HS_/64, T_/64, B_*H_), 256, 0, stream>>>(vptr, vT, T_, HS_, 0, (long)T_*HS_);

    // y[t,d] = sum_s alpha[t,s]*vT[d,s] -> yc (B,T,C) at col h*HS, bf16
    dim3 gp(T_/128, HS_/128, B_*H_);
    gemm_bf16<0,0,0,1><<<gp, 256, 0, stream>>>(alpha, vT, nullptr, nullptr, yc,
        T_, HS_, T_, T_, T_, C_, (long)T_*T_, (long)HS_*T_, (long)T_*C_, HS_, 2, (long)T_*C_);

    // x = x + yc @ proj_w + proj_b   (f32 out)
    dim3 gj(M_/128, C_/128, 1);
    gemm_bf16<1,1,0,0><<<gj, 256, 0, stream>>>(yc, projT + (long)l*C_*C_, proj_b + l*C_, x, x,
        M_, C_, C_, C_, C_, C_, 0, 0, 0, 0, 0, (long)T_*C_);

    ln_k<<<M_, 256, 0, stream>>>(x, ln2_g + l * C_, ln2_b + l * C_, xn);

    // hidden = relu(xn @ ff_w1 + b1)  bf16
    dim3 g1(M_/256, 4*C_/256, 1);
    gemm256<1,1,1,0><<<g1, 512, 0, stream>>>(xn, ff1T + (long)l*4*C_*C_, ff_b1 + (long)l*4*C_,
        hidden, C_, C_, C_, 4*C_, 0, 0, 0, (long)1024*4*C_);

    // x = x + hidden @ ff_w2 + b2   (f32 out)
    dim3 g2(M_/128, C_/128, 1);
    gemm_bf16<1,1,0,0><<<g2, 256, 0, stream>>>(hidden, ff2T + (long)l*C_*4*C_, ff_b2 + l*C_, x, x,
        M_, C_, 4*C_, 4*C_, 4*C_, C_, 0, 0, 0, 0, 0, (long)T_*C_);
  }

  ln_k<<<M_, 256, 0, stream>>>(x, lnf_g, lnf_b, xn);

  // head weight transpose into the (now dead) scores/alpha region
  transpose_k<float><<<dim3(V_/64, C_/64, 1), 256, 0, stream>>>(head_w, headT, C_, V_, 0, (long)C_*V_);

  dim3 gh(M_/256, V_/256, 1);
  gemm256<1,0,0,0><<<gh, 512, 0, stream>>>(xn, headT, head_b, outp,
      C_, C_, C_, V_, 0, 0, 0, (long)1024*V_);
}

// Round 9
// 1561.145 us; speedup vs baseline: 3.8927x; 1.0281x over previous
//
#include <hip/hip_runtime.h>

// GPT forward: L=4, H=4, C=1024, HS=256, V=32000, B=4, T=1024. f32 in/out.
// bf16 MFMA 16x16x32. Big GEMMs (head, FF1, QKV-merged, scores): 256x256-tile
// 8-wave pipelined kernel (read-ahead reg dbuf, counted vmcnt, st_16x32
// swizzle, setprio, LDS-transposed coalesced epilogue, NT stores for the
// head's streaming f32 C). Rest: 128x128 m97-structure kernel.

#define C_  1024
#define T_  1024
#define HS_ 256
#define H_  4
#define L_  4
#define V_  32000
#define B_  4
#define M_  4096   // B_*T_

typedef __attribute__((ext_vector_type(8))) short  bfx8;
typedef __attribute__((ext_vector_type(4))) float  fx4;
typedef __attribute__((ext_vector_type(4))) unsigned short usx4;
typedef __attribute__((ext_vector_type(8))) unsigned short usx8;

__device__ __forceinline__ unsigned short f2bf(float f) {
  unsigned int u = __builtin_bit_cast(unsigned int, f);
  u += 0x7fffu + ((u >> 16) & 1u);          // round-to-nearest-even
  return (unsigned short)(u >> 16);
}
__device__ __forceinline__ float bf2f(unsigned short u) {
  return __builtin_bit_cast(float, ((unsigned int)u) << 16);
}

// async global->LDS, 16 B per lane. LDS dest = (wave-uniform base) + lane*16.
__device__ __forceinline__ void gload16(const unsigned short* g, unsigned short* l) {
  __builtin_amdgcn_global_load_lds(
      (const __attribute__((address_space(1))) unsigned int*)g,
      (__attribute__((address_space(3))) unsigned int*)l, 16, 0, 0);
}

// ============================ 128x128 kernel =================================
template<int BIAS, int RES, int RELU, int OUTBF>
__global__ __launch_bounds__(256, 2) void gemm_bf16(
    const unsigned short* __restrict__ A, const unsigned short* __restrict__ Bm,
    const float* __restrict__ bias, const float* __restrict__ res,
    void* __restrict__ out,
    int M, int N, int K, int lda, int ldb, int ldc,
    long sA, long sB, long sC1, long sC2, int zShift, long rowOuter)
{
  __shared__ unsigned short As[128 * 32];
  __shared__ unsigned short Bs[128 * 32];
  const int z = blockIdx.z;
  A  += (long)z * sA;
  Bm += (long)z * sB;
  const long outOff = ((long)(z >> zShift)) * sC1 + (long)(z & ((1 << zShift) - 1)) * sC2;
  const int m0 = blockIdx.x * 128, n0 = blockIdx.y * 128;
  const int tid = threadIdx.x;
  const int lane = tid & 63, wave = tid >> 6;
  const int wm = (wave >> 1) * 64, wn = (wave & 1) * 64;
  const int fr = lane & 15, kb = lane >> 4;
  const int sr = lane >> 2;
  const int csw = (((lane & 3) ^ ((lane >> 3) & 3)) << 3);
  const int aco = ((kb ^ ((lane >> 1) & 3)) << 3);

  fx4 acc[4][4] = {};

  for (int k0 = 0; k0 < K; k0 += 32) {
    #pragma unroll
    for (int i = 0; i < 2; ++i) {
      const int c = wave * 2 + i;
      gload16(A  + (long)(m0 + c * 16 + sr) * lda + k0 + csw, &As[c * 512]);
      gload16(Bm + (long)(n0 + c * 16 + sr) * ldb + k0 + csw, &Bs[c * 512]);
    }
    __syncthreads();
    bfx8 af[4], bf[4];
    #pragma unroll
    for (int i = 0; i < 4; ++i)
      af[i] = *reinterpret_cast<const bfx8*>(&As[(wm + i * 16 + fr) * 32 + aco]);
    #pragma unroll
    for (int j = 0; j < 4; ++j)
      bf[j] = *reinterpret_cast<const bfx8*>(&Bs[(wn + j * 16 + fr) * 32 + aco]);
    #pragma unroll
    for (int i = 0; i < 4; ++i)
      #pragma unroll
      for (int j = 0; j < 4; ++j)
        acc[i][j] = __builtin_amdgcn_mfma_f32_16x16x32_bf16(af[i], bf[j], acc[i][j], 0, 0, 0);
    __syncthreads();
  }

  const float* resp = res;
  if (RES) resp += outOff;
  const int rbase = (lane >> 4) * 4;
  #pragma unroll
  for (int j = 0; j < 4; ++j) {
    const int n = n0 + wn + j * 16 + fr;
    float bv = 0.f;
    if (BIAS) bv = bias[n];
    #pragma unroll
    for (int i = 0; i < 4; ++i) {
      #pragma unroll
      for (int r = 0; r < 4; ++r) {
        const int m = m0 + wm + i * 16 + rbase + r;
        const long off = outOff + ((long)(m >> 10)) * rowOuter + (long)(m & 1023) * ldc + n;
        float val = acc[i][j][r] + bv;
        if (RELU) val = fmaxf(val, 0.f);
        if (RES) val += resp[((long)(m >> 10)) * rowOuter + (long)(m & 1023) * ldc + n];
        if (OUTBF) ((unsigned short*)out)[off] = f2bf(val);
        else       ((float*)out)[off] = val;
      }
    }
  }
}

// ============================ 256x256 pipelined kernel =======================
// 512 thr = 8 waves (2M x 4N), wave tile 128x64, BK=64 (2 ksteps of 32).
// LDS: 8 slots [256 rows][32 K] bf16: A(par,kh) @ (par*2+kh)*8192, B @ +32768.
// Region q: {stage 1 half-tile; ds_reads for region q+1 (alt reg set);
// 16 MFMA on current set; lgkmcnt(0)+schedbar; [even q] vmcnt(8); s_barrier}.
#define BAR() __builtin_amdgcn_s_barrier()
#define LGKM() { asm volatile("s_waitcnt lgkmcnt(0)" ::: "memory"); \
                 __builtin_amdgcn_sched_barrier(0); }
#define VM8()  asm volatile("s_waitcnt vmcnt(8)" ::: "memory")
#define STA(tau, kh) { const int tc = (tau) < NT ? (tau) : NT - 1; \
  const unsigned short* src = A + (long)(m0 + wave * 16 + srow) * lda + tc * 64 + (kh) * 32 + csw; \
  unsigned short* d = &S[(((tau) & 1) * 2 + (kh)) * 8192 + wave * 512]; \
  gload16(src, d); gload16(src + (long)128 * lda, d + 4096); }
#define STB(tau, kh) { const int tc = (tau) < NT ? (tau) : NT - 1; \
  const unsigned short* src = Bm + (long)(n0 + wave * 16 + srow) * ldb + tc * 64 + (kh) * 32 + csw; \
  unsigned short* d = &S[32768 + (((tau) & 1) * 2 + (kh)) * 8192 + wave * 512]; \
  gload16(src, d); gload16(src + (long)128 * ldb, d + 4096); }
#define RDA(dst, par, kh, rh) { _Pragma("unroll") for (int i = 0; i < 4; ++i) \
  dst[i] = *reinterpret_cast<const bfx8*>(&S[((par)*2+(kh))*8192 + (wr*128 + (rh)*64 + i*16 + fr)*32 + aco]); }
#define RDB(dst, par, kh) { _Pragma("unroll") for (int j = 0; j < 4; ++j) \
  dst[j] = *reinterpret_cast<const bfx8*>(&S[32768 + ((par)*2+(kh))*8192 + (wc*64 + j*16 + fr)*32 + aco]); }
#define MM(rh, afx, bfx) { __builtin_amdgcn_s_setprio(1); \
  _Pragma("unroll") for (int i = 0; i < 4; ++i) { _Pragma("unroll") for (int j = 0; j < 4; ++j) \
    acc[(rh)*4+i][j] = __builtin_amdgcn_mfma_f32_16x16x32_bf16(afx[i], bfx[j], acc[(rh)*4+i][j], 0, 0, 0); } \
  __builtin_amdgcn_s_setprio(0); }

// EPI 0: out addr = outOff + m*ldc + n (linear). NT f32 stores when !OUTBF.
// EPI 1: QKV coalesced: block-uniform (sel,h,bq) base, ldc=HS_, bf16.
template<int BIAS, int RELU, int OUTBF, int EPI>
__global__ __launch_bounds__(512, 2) void gemm256(
    const unsigned short* __restrict__ A, const unsigned short* __restrict__ Bm,
    const float* __restrict__ bias, void* __restrict__ out,
    int K, int lda, int ldb, int ldc, long sA, long sB, long sC1)
{
  __shared__ unsigned short S[65536];   // 128 KB
  const int z = blockIdx.z;
  A  += (long)z * sA;
  Bm += (long)z * sB;
  const long outOff = (long)z * sC1;
  const int m0 = blockIdx.x * 256, n0 = blockIdx.y * 256;
  const int tid = threadIdx.x;
  const int lane = tid & 63, wave = tid >> 6;
  const int wr = wave >> 2, wc = wave & 3;
  const int fr = lane & 15, kb = lane >> 4;
  const int srow = lane >> 2;
  // st_16x32: 16B slot-in-row ^= ((row&15)>>3)<<1. Pre-swizzled global source.
  const int csw = (((lane & 3) ^ (((lane >> 5) & 1) << 1)) << 3);
  const int aco = ((kb ^ (((fr >> 3) & 1) << 1)) << 3);
  const int NT = K >> 6;    // K-tiles of 64 (NT even for all our shapes)
  const int NI = NT >> 1;

  fx4 acc[8][4] = {};
  bfx8 afa[4], afb[4], bf0[4], bf1[4];

  // prologue: stage ktiles 0,1 fully (8 half-tiles, consumption order)
  STB(0, 0); STA(0, 0); STB(0, 1); STA(0, 1);
  STB(1, 0); STA(1, 0); STB(1, 1); STA(1, 1);
  VM8();                      // oldest 8 done: (0,0)+(0,1) A&B landed
  BAR();
  RDA(afa, 0, 0, 0); RDB(bf1, 0, 0);   // regs for region r1's MFMA
  LGKM();
  BAR();

  for (int t = 0; t < NI; ++t) {
    const int u = 2 * t;
    STB(u + 2, 0); RDA(afb, 0, 0, 1);                 MM(0, afa, bf1); LGKM(); BAR();
    STA(u + 2, 0); RDA(afa, 0, 1, 0); RDB(bf0, 0, 1); MM(1, afb, bf1); LGKM(); VM8(); BAR();
    STB(u + 2, 1); RDA(afb, 0, 1, 1);                 MM(0, afa, bf0); LGKM(); BAR();
    STA(u + 2, 1); RDA(afa, 1, 0, 0); RDB(bf1, 1, 0); MM(1, afb, bf0); LGKM(); VM8(); BAR();
    STB(u + 3, 0); RDA(afb, 1, 0, 1);                 MM(0, afa, bf1); LGKM(); BAR();
    STA(u + 3, 0); RDA(afa, 1, 1, 0); RDB(bf0, 1, 1); MM(1, afb, bf1); LGKM(); VM8(); BAR();
    STB(u + 3, 1); RDA(afb, 1, 1, 1);                 MM(0, afa, bf0); LGKM(); BAR();
    STA(u + 3, 1); RDA(afa, 0, 0, 0); RDB(bf1, 0, 0); MM(1, afb, bf0); LGKM(); VM8(); BAR();
  }
  asm volatile("s_waitcnt vmcnt(0)" ::: "memory");  // drain dangling prefetches
  BAR();   // no in-flight gload may write S while epilogue reuses it

  // ---- LDS-transposed coalesced epilogue (all variants) ----
  // Each wave round-trips its 128x64 quadrant (two 128x32 halves) through its
  // private 16 KB LDS region; word-col XOR by ((row&7)<<2).
  const int rbase = (lane >> 4) * 4;
  unsigned short* dst1 = nullptr;
  if (EPI == 1) {
    const int sel = n0 >> 10, h = (n0 >> 8) & 3;
    const int bq = m0 >> 10, tq0 = m0 & 1023;
    dst1 = (unsigned short*)out + ((long)sel * B_ + bq) * H_ * T_ * HS_
         + (long)h * T_ * HS_ + (long)tq0 * HS_;
  }
  float* lf = (float*)S;
  #pragma unroll
  for (int jh = 0; jh < 2; ++jh) {
    #pragma unroll
    for (int jj = 0; jj < 2; ++jj)
      #pragma unroll
      for (int i = 0; i < 8; ++i)
        #pragma unroll
        for (int r = 0; r < 4; ++r) {
          const int row = i * 16 + rbase + r;
          const int cw = (jj * 16 + fr) ^ ((row & 7) << 2);
          lf[wave * 4096 + row * 32 + cw] = acc[i][jh * 2 + jj][r];
        }
    #pragma unroll
    for (int rs = 0; rs < 16; ++rs) {
      const int row = rs * 8 + (lane >> 3);
      const int c0 = (lane & 7) * 4;
      const int cw = c0 ^ ((row & 7) << 2);
      fx4 val = *reinterpret_cast<const fx4*>(&lf[wave * 4096 + row * 32 + cw]);
      const int nl = wc * 64 + jh * 32 + c0;           // n - n0
      if (BIAS) {
        const float4 bb = *reinterpret_cast<const float4*>(bias + n0 + nl);
        val[0] += bb.x; val[1] += bb.y; val[2] += bb.z; val[3] += bb.w;
      }
      if (RELU) {
        val[0] = fmaxf(val[0], 0.f); val[1] = fmaxf(val[1], 0.f);
        val[2] = fmaxf(val[2], 0.f); val[3] = fmaxf(val[3], 0.f);
      }
      if (EPI == 1) {
        const long off = (long)(wr * 128 + row) * HS_ + nl;
        usx4 o = { f2bf(val[0]), f2bf(val[1]), f2bf(val[2]), f2bf(val[3]) };
        *reinterpret_cast<usx4*>(dst1 + off) = o;
      } else {
        const long off = outOff + (long)(m0 + wr * 128 + row) * ldc + n0 + nl;
        if (OUTBF) {
          usx4 o = { f2bf(val[0]), f2bf(val[1]), f2bf(val[2]), f2bf(val[3]) };
          *reinterpret_cast<usx4*>((unsigned short*)out + off) = o;
        } else {
          __builtin_nontemporal_store(val, reinterpret_cast<fx4*>((float*)out + off));
        }
      }
    }
    __builtin_amdgcn_sched_barrier(0);  // keep jh=1 writes after jh=0 reads
  }
}

// Tiled transpose + convert-to-bf16. src: (batch zb, R, Cc) TIN;
// dst base: dst + (zb>>zShiftT)*sOuter + (zb&mask)*(R*Cc); writes (Cc,R) bf16.
template<typename TIN>
__global__ __launch_bounds__(256) void transpose_k(const TIN* __restrict__ src,
    unsigned short* __restrict__ dst, int R, int Cc, int zShiftT, long sOuter) {
  __shared__ float ts[64][65];
  const long zb = blockIdx.z;
  src += zb * (long)R * Cc;
  dst += (zb >> zShiftT) * sOuter + (zb & ((1 << zShiftT) - 1)) * ((long)R * Cc);
  const int r0 = blockIdx.y * 64, c0 = blockIdx.x * 64;
  const int tr = threadIdx.x >> 4;
  const int tc = (threadIdx.x & 15) * 4;
  #pragma unroll
  for (int it = 0; it < 4; ++it) {
    const int r = tr + it * 16;
    float4 v;
    if constexpr (sizeof(TIN) == 4) {
      v = *reinterpret_cast<const float4*>(src + (long)(r0 + r) * Cc + c0 + tc);
    } else {
      usx4 u = *reinterpret_cast<const usx4*>(src + (long)(r0 + r) * Cc + c0 + tc);
      v.x = bf2f(u[0]); v.y = bf2f(u[1]); v.z = bf2f(u[2]); v.w = bf2f(u[3]);
    }
    ts[r][tc + 0] = v.x; ts[r][tc + 1] = v.y; ts[r][tc + 2] = v.z; ts[r][tc + 3] = v.w;
  }
  __syncthreads();
  #pragma unroll
  for (int it = 0; it < 4; ++it) {
    const int cj = tr + it * 16;
    usx4 o = { f2bf(ts[tc + 0][cj]), f2bf(ts[tc + 1][cj]),
               f2bf(ts[tc + 2][cj]), f2bf(ts[tc + 3][cj]) };
    *reinterpret_cast<usx4*>(dst + (long)(c0 + cj) * R + r0 + tc) = o;
  }
}

__global__ __launch_bounds__(256) void embed_k(const int* __restrict__ idx,
                                               const float* __restrict__ tok,
                                               const float* __restrict__ pos,
                                               float* __restrict__ x) {
  const int row = blockIdx.x;
  const int t = row & (T_ - 1);
  const int id = idx[row];
  const int c = threadIdx.x * 4;
  const float4 a = *reinterpret_cast<const float4*>(tok + (long)id * C_ + c);
  const float4 p = *reinterpret_cast<const float4*>(pos + (long)t * C_ + c);
  float4 ov = { a.x + p.x, a.y + p.y, a.z + p.z, a.w + p.w };
  *reinterpret_cast<float4*>(x + (long)row * C_ + c) = ov;
}

// LayerNorm: f32 in, bf16 out.
__global__ __launch_bounds__(256) void ln_k(const float* __restrict__ x,
                                            const float* __restrict__ g,
                                            const float* __restrict__ b,
                                            unsigned short* __restrict__ o) {
  __shared__ float red[8];
  const int row = blockIdx.x;
  const int c = threadIdx.x * 4;
  const float4 v = *reinterpret_cast<const float4*>(x + (long)row * C_ + c);
  float s1 = v.x + v.y + v.z + v.w;
  float s2 = v.x * v.x + v.y * v.y + v.z * v.z + v.w * v.w;
  #pragma unroll
  for (int off = 32; off; off >>= 1) {
    s1 += __shfl_xor(s1, off, 64);
    s2 += __shfl_xor(s2, off, 64);
  }
  const int lane = threadIdx.x & 63, w = threadIdx.x >> 6;
  if (lane == 0) { red[w] = s1; red[4 + w] = s2; }
  __syncthreads();
  s1 = red[0] + red[1] + red[2] + red[3];
  s2 = red[4] + red[5] + red[6] + red[7];
  const float mu = s1 * (1.f / C_);
  float var = s2 * (1.f / C_) - mu * mu;
  var = fmaxf(var, 0.f);
  const float inv = rsqrtf(var + 1e-5f);
  const float4 gg = *reinterpret_cast<const float4*>(g + c);
  const float4 bb = *reinterpret_cast<const float4*>(b + c);
  usx4 ov;
  ov[0] = f2bf((v.x - mu) * inv * gg.x + bb.x);
  ov[1] = f2bf((v.y - mu) * inv * gg.y + bb.y);
  ov[2] = f2bf((v.z - mu) * inv * gg.z + bb.z);
  ov[3] = f2bf((v.w - mu) * inv * gg.w + bb.w);
  *reinterpret_cast<usx4*>(o + (long)row * C_ + c) = ov;
}

// Fused column-softmax + transpose. In: S^T (z, s, t) bf16. Out: alpha (z, t, s)
// bf16, alpha[t][s] = softmax over t of masked(S^T[s][t] * 1/32).
// Block: 64 s-rows x full T. 3 passes (max, Z, write-transposed via LDS tiles).
__global__ __launch_bounds__(256) void colsmT_k(const unsigned short* __restrict__ sc,
                                                unsigned short* __restrict__ alpha) {
  __shared__ float ms[64], invs[64];
  __shared__ float tile[64][65];
  const int z = blockIdx.z;
  const int s0 = blockIdx.x * 64;
  const int r = threadIdx.x >> 2;       // 0..63 (s-local)
  const int tq = threadIdx.x & 3;       // t-quarter
  const int s = s0 + r;
  const unsigned short* p = sc + (long)z * T_ * T_ + (long)s * T_ + tq * 256;
  const float scale = 0.03125f;

  // pass 1: masked max over t
  float m = -1e30f;
  for (int i = 0; i < 32; ++i) {
    const usx8 u = *reinterpret_cast<const usx8*>(p + i * 8);
    #pragma unroll
    for (int j = 0; j < 8; ++j) {
      const int t = tq * 256 + i * 8 + j;
      if (t >= s) m = fmaxf(m, bf2f(u[j]) * scale);
    }
  }
  m = fmaxf(m, __shfl_xor(m, 1, 64));
  m = fmaxf(m, __shfl_xor(m, 2, 64));
  if (tq == 0) ms[r] = m;
  __syncthreads();
  m = ms[r];

  // pass 2: Z
  float zsum = 0.f;
  for (int i = 0; i < 32; ++i) {
    const usx8 u = *reinterpret_cast<const usx8*>(p + i * 8);
    #pragma unroll
    for (int j = 0; j < 8; ++j) {
      const int t = tq * 256 + i * 8 + j;
      if (t >= s) zsum += __expf(bf2f(u[j]) * scale - m);
    }
  }
  zsum += __shfl_xor(zsum, 1, 64);
  zsum += __shfl_xor(zsum, 2, 64);
  if (tq == 0) invs[r] = 1.f / zsum;
  __syncthreads();
  const float inv = invs[r];

  // pass 3: 16 t-chunks of 64; recompute alpha, LDS-transpose, coalesced write
  const unsigned short* prow = sc + (long)z * T_ * T_ + (long)s * T_;
  unsigned short* ob = alpha + (long)z * T_ * T_ + s0;
  const int wrow = threadIdx.x >> 2;    // t-local on write
  const int seg  = threadIdx.x & 3;     // s-16-segment on write
  for (int tc = 0; tc < 16; ++tc) {
    #pragma unroll
    for (int half = 0; half < 2; ++half) {
      const int tb = tc * 64 + tq * 16 + half * 8;
      const usx8 u = *reinterpret_cast<const usx8*>(prow + tb);
      #pragma unroll
      for (int j = 0; j < 8; ++j) {
        const int t = tb + j;
        const float a = (t >= s) ? __expf(bf2f(u[j]) * scale - m) * inv : 0.f;
        tile[tq * 16 + half * 8 + j][r] = a;
      }
    }
    __syncthreads();
    usx8 o0, o1;
    #pragma unroll
    for (int k = 0; k < 8; ++k) o0[k] = f2bf(tile[wrow][seg * 16 + k]);
    #pragma unroll
    for (int k = 0; k < 8; ++k) o1[k] = f2bf(tile[wrow][seg * 16 + 8 + k]);
    unsigned short* od = ob + (long)(tc * 64 + wrow) * T_ + seg * 16;
    *reinterpret_cast<usx8*>(od) = o0;
    *reinterpret_cast<usx8*>(od + 8) = o1;
    __syncthreads();
  }
}

extern "C" void kernel_launch(void* const* d_in, const int* in_sizes, int n_in,
                              void* d_out, int out_size, void* d_ws, size_t ws_size,
                              hipStream_t stream) {
  const int*   idx    = (const int*)d_in[0];
  const float* tok    = (const float*)d_in[1];
  const float* pos    = (const float*)d_in[2];
  const float* wq     = (const float*)d_in[3];
  const float* wk     = (const float*)d_in[4];
  const float* wv     = (const float*)d_in[5];
  const float* proj_w = (const float*)d_in[6];
  const float* proj_b = (const float*)d_in[7];
  const float* ln1_g  = (const float*)d_in[8];
  const float* ln1_b  = (const float*)d_in[9];
  const float* ln2_g  = (const float*)d_in[10];
  const float* ln2_b  = (const float*)d_in[11];
  const float* ff_w1  = (const float*)d_in[12];
  const float* ff_b1  = (const float*)d_in[13];
  const float* ff_w2  = (const float*)d_in[14];
  const float* ff_b2  = (const float*)d_in[15];
  const float* lnf_g  = (const float*)d_in[16];
  const float* lnf_b  = (const float*)d_in[17];
  const float* head_w = (const float*)d_in[18];
  const float* head_b = (const float*)d_in[19];
  float* outp = (float*)d_out;

  typedef unsigned short us;
  char* w = (char*)d_ws;
  float* x    = (float*)(w + 0);            // 16 MB (M,C) f32
  us* xn      = (us*)(w + 16777216);        //  8 MB (M,C)
  us* qkv     = (us*)(w + 25165824);        // 24 MB: q,k,v each (B,H,T,HS)
  us* kptr    = qkv + 4194304;
  us* vptr    = qkv + 8388608;
  us* vT      = (us*)(w + 50331648);        //  8 MB (B,H,HS,T)
  us* yc      = (us*)(w + 58720256);        //  8 MB (B,T,C)
  us* sc      = (us*)(w + 67108864);        // 32 MB (B*H,T,T) scores S^T
  us* headT   = (us*)(w + 67108864);        // 65.5 MB alias over sc+alpha
  us* alpha   = (us*)(w + 100663296);       // 32 MB (B*H,T,T)
  us* hidden  = (us*)(w + 134217728);       // 32 MB (M,4C)
  us* wqkvT   = (us*)(w + 167772160);       // 24 MB (L,3,H,HS,C)
  us* projT   = (us*)(w + 192937984);       //  8 MB (L,C,C)
  us* ff1T    = (us*)(w + 201326592);       // 32 MB (L,4C,C)
  us* ff2T    = (us*)(w + 234881024);       // 32 MB (L,C,4C)
  if (ws_size < (size_t)268435456) return;  // fail loudly

  const long HHC = (long)H_ * HS_ * C_;     // per-matrix per-layer us
  // ---- one-time weight transpose + bf16 convert ----
  transpose_k<float><<<dim3(HS_/64, C_/64, L_*H_), 256, 0, stream>>>(wq, wqkvT,           C_, HS_, 2, 3*HHC);
  transpose_k<float><<<dim3(HS_/64, C_/64, L_*H_), 256, 0, stream>>>(wk, wqkvT + HHC,     C_, HS_, 2, 3*HHC);
  transpose_k<float><<<dim3(HS_/64, C_/64, L_*H_), 256, 0, stream>>>(wv, wqkvT + 2*HHC,   C_, HS_, 2, 3*HHC);
  transpose_k<float><<<dim3(C_/64, C_/64, L_), 256, 0, stream>>>(proj_w, projT, C_, C_, 0, (long)C_*C_);
  transpose_k<float><<<dim3(4*C_/64, C_/64, L_), 256, 0, stream>>>(ff_w1, ff1T, C_, 4*C_, 0, (long)C_*4*C_);
  transpose_k<float><<<dim3(C_/64, 4*C_/64, L_), 256, 0, stream>>>(ff_w2, ff2T, 4*C_, C_, 0, (long)4*C_*C_);

  embed_k<<<M_, 256, 0, stream>>>(idx, tok, pos, x);

  for (int l = 0; l < L_; ++l) {
    ln_k<<<M_, 256, 0, stream>>>(x, ln1_g + l * C_, ln1_b + l * C_, xn);

    // merged QKV: N=3072, coalesced (sel,h)-based epilogue -> qkv (3,B,H,T,HS)
    dim3 gqkv(M_/256, 3*C_/256, 1);
    gemm256<0,0,1,1><<<gqkv, 512, 0, stream>>>(xn, wqkvT + l * 3 * HHC, nullptr, qkv,
        C_, C_, C_, 0, 0, 0, 0);

    // S^T[s][t] = sum_d K[s,d]*Q[t,d]  -> bf16 (scale applied in colsmT)
    dim3 gs(T_/256, T_/256, B_*H_);
    gemm256<0,0,1,0><<<gs, 512, 0, stream>>>(kptr, qkv, nullptr, sc,
        HS_, HS_, HS_, T_, (long)T_*HS_, (long)T_*HS_, (long)T_*T_);

    // fused softmax-over-t + transpose -> alpha (z, t, s)
    colsmT_k<<<dim3(T_/64, 1, B_*H_), 256, 0, stream>>>(sc, alpha);

    // v (t,d) -> vT (d,t)
    transpose_k<us><<<dim3(HS_/64, T_/64, B_*H_), 256, 0, stream>>>(vptr, vT, T_, HS_, 0, (long)T_*HS_);

    // y[t,d] = sum_s alpha[t,s]*vT[d,s] -> yc (B,T,C) at col h*HS, bf16
    dim3 gp(T_/128, HS_/128, B_*H_);
    gemm_bf16<0,0,0,1><<<gp, 256, 0, stream>>>(alpha, vT, nullptr, nullptr, yc,
        T_, HS_, T_, T_, T_, C_, (long)T_*T_, (long)HS_*T_, (long)T_*C_, HS_, 2, (long)T_*C_);

    // x = x + yc @ proj_w + proj_b   (f32 out)
    dim3 gj(M_/128, C_/128, 1);
    gemm_bf16<1,1,0,0><<<gj, 256, 0, stream>>>(yc, projT + (long)l*C_*C_, proj_b + l*C_, x, x,
        M_, C_, C_, C_, C_, C_, 0, 0, 0, 0, 0, (long)T_*C_);

    ln_k<<<M_, 256, 0, stream>>>(x, ln2_g + l * C_, ln2_b + l * C_, xn);

    // hidden = relu(xn @ ff_w1 + b1)  bf16
    dim3 g1(M_/256, 4*C_/256, 1);
    gemm256<1,1,1,0><<<g1, 512, 0, stream>>>(xn, ff1T + (long)l*4*C_*C_, ff_b1 + (long)l*4*C_,
        hidden, C_, C_, C_, 4*C_, 0, 0, 0);

    // x = x + hidden @ ff_w2 + b2   (f32 out)
    dim3 g2(M_/128, C_/128, 1);
    gemm_bf16<1,1,0,0><<<g2, 256, 0, stream>>>(hidden, ff2T + (long)l*C_*4*C_, ff_b2 + l*C_, x, x,
        M_, C_, 4*C_, 4*C_, 4*C_, C_, 0, 0, 0, 0, 0, (long)T_*C_);
  }

  ln_k<<<M_, 256, 0, stream>>>(x, lnf_g, lnf_b, xn);

  // head weight transpose into the (now dead) scores/alpha region
  transpose_k<float><<<dim3(V_/64, C_/64, 1), 256, 0, stream>>>(head_w, headT, C_, V_, 0, (long)C_*V_);

  dim3 gh(M_/256, V_/256, 1);
  gemm256<1,0,0,0><<<gh, 512, 0, stream>>>(xn, headT, head_b, outp,
      C_, C_, C_, V_, 0, 0, 0);
}